// Round 4
// baseline (582.870 us; speedup 1.0000x reference)
//
#include <hip/hip_runtime.h>
#include <hip/hip_bf16.h>
#include <math.h>

#define B_ 16
#define T_ 4096
#define D_ 1024
#define U_ 1024
#define M_ (B_*T_)   // 65536

typedef __attribute__((ext_vector_type(8))) short short8;
typedef __attribute__((ext_vector_type(4))) short short4v;
typedef __attribute__((ext_vector_type(4))) float float4v;

static __device__ __forceinline__ short f2bf(float f) {
    unsigned u = __builtin_bit_cast(unsigned, f);
    u += 0x7FFFu + ((u >> 16) & 1u);   // RNE
    return (short)(u >> 16);
}
static __device__ __forceinline__ float bf2f(short s) {
    unsigned u = ((unsigned)(unsigned short)s) << 16;
    return __builtin_bit_cast(float, u);
}
static __device__ __forceinline__ float fast_tanh(float x) {
    float c = fminf(fmaxf(2.f * x, -30.f), 30.f);
    float t = __expf(c);
    return __fdividef(t - 1.f, t + 1.f);
}

#define GLLDS(GP, LP) __builtin_amdgcn_global_load_lds( \
    (const __attribute__((address_space(1))) void*)(GP), \
    (__attribute__((address_space(3))) void*)(LP), 16, 0, 0)

// ---------------- kernel 1 (fused prep): hb partials + W2 transpose/convert + enc convert
__global__ void prep_fused(const float* __restrict__ h, const float* __restrict__ W1,
                           const float* __restrict__ b1, const float* __restrict__ b2,
                           const float* __restrict__ W2, const float* __restrict__ enc,
                           float* __restrict__ hbp, short* __restrict__ W2T,
                           short* __restrict__ encbf) {
    int bx = blockIdx.x;
    if (bx >= 512) {
        // ---- convert_enc
        size_t g = (size_t)(bx - 512) * 256 + threadIdx.x;
        const float4v* p = (const float4v*)(enc + g * 16);
        float4v f0 = p[0], f1 = p[1], f2 = p[2], f3 = p[3];
        short8 a, b;
        a[0]=f2bf(f0[0]); a[1]=f2bf(f0[1]); a[2]=f2bf(f0[2]); a[3]=f2bf(f0[3]);
        a[4]=f2bf(f1[0]); a[5]=f2bf(f1[1]); a[6]=f2bf(f1[2]); a[7]=f2bf(f1[3]);
        b[0]=f2bf(f2[0]); b[1]=f2bf(f2[1]); b[2]=f2bf(f2[2]); b[3]=f2bf(f2[3]);
        b[4]=f2bf(f3[0]); b[5]=f2bf(f3[1]); b[6]=f2bf(f3[2]); b[7]=f2bf(f3[3]);
        short8* q = (short8*)(encbf + g * 16);
        q[0] = a; q[1] = b;
    } else if (bx < 256) {
        // ---- hb partials, K split 4 ways
        int kc = bx >> 6;
        int gid = (bx & 63) * 256 + threadIdx.x;
        int b = gid >> 10, u = gid & 1023;
        const float* hr = h + b * D_ + kc * 256;
        const float* w = W1 + (size_t)(kc * 256) * U_ + u;
        float s0 = 0.f, s1 = 0.f, s2 = 0.f, s3 = 0.f;
        for (int k = 0; k < 256; k += 4) {
            s0 += hr[k+0] * w[(size_t)(k+0) * U_];
            s1 += hr[k+1] * w[(size_t)(k+1) * U_];
            s2 += hr[k+2] * w[(size_t)(k+2) * U_];
            s3 += hr[k+3] * w[(size_t)(k+3) * U_];
        }
        float s = ((s0 + s1) + (s2 + s3));
        if (kc == 0) s += b1[u] + b2[u];
        hbp[kc * 16384 + gid] = s;
    } else {
        // ---- convert_w2t (transpose to [U][D])
        __shared__ short t[64][65];
        int x = bx - 256;
        int k0 = (x >> 4) * 64, u0 = (x & 15) * 64;
        int tx = threadIdx.x & 63, ty = threadIdx.x >> 6;
        #pragma unroll
        for (int r = 0; r < 16; ++r) {
            int kk = ty * 16 + r;
            t[kk][tx] = f2bf(W2[(size_t)(k0 + kk) * U_ + u0 + tx]);
        }
        __syncthreads();
        #pragma unroll
        for (int r = 0; r < 16; ++r) {
            int uu = ty * 16 + r;
            W2T[(size_t)(u0 + uu) * D_ + k0 + tx] = t[tx][uu];
        }
    }
}

// ---------------- kernel 2: PERSISTENT 256x256-tile 8-phase bf16 GEMM + tanh*V epilogue.
// Grid 256 = 1 block/CU. Each block: fixed (XCD c, group gi, ntile nt); walks 4 mtiles
// (s=0..3, mtile = s*64 + c*8 + gi) under ONE continuous counted-vmcnt pipeline =
// 64 virtual K-tiles. Staging is UNCONDITIONAL: B-tile index wraps (kt+2)&15 (B panel
// is sub-invariant -> wrapped stages are correct next-sub data); A clamps aN=aS at s==3
// (harmless real reads, never consumed). Epilogue hoisted out of the kt-loop, once per
// s; its scorepart store forces vmcnt(0) (stores share vmcnt -> counted waits after an
// un-drained store would be unsound), which also guarantees next-sub tiles 0/1 landed.
// Per-XCD L2: 8 A-panels (4 MB) x 4 concurrent nt-readers.
__global__ __launch_bounds__(512, 2) void gemm_score_8ph(
    const short* __restrict__ Abf,   // enc bf16 [M_, D_]
    const short* __restrict__ W2T,   // bf16 [U_, D_]
    const float* __restrict__ hbp,   // [4][B_, U_]
    const float* __restrict__ V,
    float* __restrict__ scorepart)   // [4][M_]
{
    __shared__ __align__(16) short lds[65536];   // A: [0,32768), B: [32768,65536) shorts
    __shared__ float sbuf[1024];                 // epilogue scratch (staging bufs stay live!)

    const int tid = threadIdx.x;
    const int g = blockIdx.x;
    const int c = g & 7;                        // XCD (256 % 8 == 0 -> bijective)
    const int q = g >> 3;                       // 0..31
    const int gi = q >> 2;                      // group 0..7
    const int nt = q & 3;                       // ntile fixed per block
    const int n0 = nt * 256;

    const int lane = tid & 63;
    const int wv = tid >> 6;
    const int wm = wv >> 2, wn = wv & 3;        // 2M x 4N waves
    const int lm = lane & 15, quad = lane >> 4;

    // staging geometry: one GLLDS round = 512 thr x 16B = 64 rows x 128B
    const int srow = tid >> 3;                  // row within 64-row round
    const int lslot = (tid & 7) ^ (srow & 7);   // inverse swizzle on the GLOBAL source
    const short* bS = W2T + (size_t)(n0 + srow) * D_ + lslot * 8;   // B base sub-invariant
    short* aD = lds + tid * 8;                  // linear LDS dest
    short* bD = lds + 32768 + tid * 8;

#define STG_A(base, kt, hh, bf) do { \
    GLLDS((base) + (size_t)((hh) * 128) * D_ + (kt) * 64,      aD + (bf) * 16384 + (hh) * 8192); \
    GLLDS((base) + (size_t)((hh) * 128 + 64) * D_ + (kt) * 64, aD + (bf) * 16384 + (hh) * 8192 + 4096); \
} while (0)
#define STG_B(kt, hh, bf) do { \
    GLLDS(bS + (size_t)((hh) * 128) * D_ + (kt) * 64,      bD + (bf) * 16384 + (hh) * 8192); \
    GLLDS(bS + (size_t)((hh) * 128 + 64) * D_ + (kt) * 64, bD + (bf) * 16384 + (hh) * 8192 + 4096); \
} while (0)
#define LDS_RD(off) (*(const short8*)(lds + (off)))
#define MFMA(a, b, c) __builtin_amdgcn_mfma_f32_16x16x32_bf16((a), (b), (c), 0, 0, 0)

    // swizzled read bases
    const int aB0 = (wm * 128 + lm) * 64 + (quad ^ (lm & 7)) * 8;
    const int aB1 = aB0 ^ 32;
    const int bB0 = 32768 + (wn * 64 + lm) * 64 + (quad ^ (lm & 7)) * 8;
    const int bB1 = bB0 ^ 32;

    float4v acc[8][4] = {};
    short8 Af[4][2], Bf[4][2];

    float Vv[4];
    #pragma unroll
    for (int ni = 0; ni < 4; ++ni) Vv[ni] = V[n0 + wn * 64 + ni * 16 + lm];

    const int mtile0 = (c << 3) + gi;           // sub s: mtile = s*64 + mtile0
    const ptrdiff_t subStride = (ptrdiff_t)16384 * D_;   // 64 mtiles * 256 rows
    const short* aS = Abf + (size_t)(mtile0 * 256 + srow) * D_ + lslot * 8;

    // ---- prologue: tile0 all 4 halves, then tile1 {B-lo, A-lo, B-hi} (6 in flight)
    STG_A(aS, 0, 0, 0); STG_A(aS, 0, 1, 0); STG_B(0, 0, 0); STG_B(0, 1, 0);
    STG_B(1, 0, 1); STG_A(aS, 1, 0, 1); STG_B(1, 1, 1);
    asm volatile("s_waitcnt vmcnt(6)" ::: "memory");
    __builtin_amdgcn_s_barrier();
    __builtin_amdgcn_sched_barrier(0);

    #pragma unroll 1
    for (int s = 0; s < 4; ++s) {
        const short* aC = aS;
        const short* aN = (s < 3) ? (aS + subStride) : aS;   // clamp: s==3 stages are never consumed
        for (int kt = 0; kt < 16; ++kt) {
            const int buf = kt & 1;
            const int ab = buf * 16384;
            // ---------- phase 0: read A-lo + B-lo frags (12 ds_read), stage A-hi(kt+1)
            #pragma unroll
            for (int mi = 0; mi < 4; ++mi) {
                Af[mi][0] = LDS_RD(ab + aB0 + mi * 1024);
                Af[mi][1] = LDS_RD(ab + aB1 + mi * 1024);
            }
            #pragma unroll
            for (int ni = 0; ni < 2; ++ni) {
                Bf[ni][0] = LDS_RD(ab + bB0 + ni * 1024);
                Bf[ni][1] = LDS_RD(ab + bB1 + ni * 1024);
            }
            STG_A((kt == 15 ? aN : aC), (kt + 1) & 15, 1, (kt + 1) & 1);
            __builtin_amdgcn_s_barrier();
            __builtin_amdgcn_s_setprio(1);
            #pragma unroll
            for (int mi = 0; mi < 4; ++mi)
                #pragma unroll
                for (int ni = 0; ni < 2; ++ni) {
                    acc[mi][ni] = MFMA(Af[mi][0], Bf[ni][0], acc[mi][ni]);
                    acc[mi][ni] = MFMA(Af[mi][1], Bf[ni][1], acc[mi][ni]);
                }
            __builtin_amdgcn_s_setprio(0);
            __builtin_amdgcn_s_barrier();
            // ---------- phase 1: read B-hi frags (4 ds_read)
            #pragma unroll
            for (int ni = 0; ni < 2; ++ni) {
                Bf[2 + ni][0] = LDS_RD(ab + bB0 + (2 + ni) * 1024);
                Bf[2 + ni][1] = LDS_RD(ab + bB1 + (2 + ni) * 1024);
            }
            __builtin_amdgcn_s_barrier();
            __builtin_amdgcn_s_setprio(1);
            #pragma unroll
            for (int mi = 0; mi < 4; ++mi)
                #pragma unroll
                for (int ni = 0; ni < 2; ++ni) {
                    acc[mi][2 + ni] = MFMA(Af[mi][0], Bf[2 + ni][0], acc[mi][2 + ni]);
                    acc[mi][2 + ni] = MFMA(Af[mi][1], Bf[2 + ni][1], acc[mi][2 + ni]);
                }
            __builtin_amdgcn_s_setprio(0);
            __builtin_amdgcn_s_barrier();
            // ---------- phase 2: read A-hi frags (8 ds_read), stage B-lo(kt+2)
            #pragma unroll
            for (int mi = 0; mi < 4; ++mi) {
                Af[mi][0] = LDS_RD(ab + aB0 + 4096 + mi * 1024);
                Af[mi][1] = LDS_RD(ab + aB1 + 4096 + mi * 1024);
            }
            STG_B((kt + 2) & 15, 0, buf);
            __builtin_amdgcn_s_barrier();
            __builtin_amdgcn_s_setprio(1);
            #pragma unroll
            for (int mi = 0; mi < 4; ++mi)
                #pragma unroll
                for (int ni = 0; ni < 2; ++ni) {
                    acc[4 + mi][ni] = MFMA(Af[mi][0], Bf[ni][0], acc[4 + mi][ni]);
                    acc[4 + mi][ni] = MFMA(Af[mi][1], Bf[ni][1], acc[4 + mi][ni]);
                }
            __builtin_amdgcn_s_setprio(0);
            __builtin_amdgcn_s_barrier();
            // ---------- phase 3: stage A-lo(kt+2)+B-hi(kt+2)
            STG_A((kt >= 14 ? aN : aC), (kt + 2) & 15, 0, buf);
            STG_B((kt + 2) & 15, 1, buf);
            __builtin_amdgcn_s_barrier();
            __builtin_amdgcn_s_setprio(1);
            #pragma unroll
            for (int mi = 0; mi < 4; ++mi)
                #pragma unroll
                for (int ni = 0; ni < 2; ++ni) {
                    acc[4 + mi][2 + ni] = MFMA(Af[mi][0], Bf[2 + ni][0], acc[4 + mi][2 + ni]);
                    acc[4 + mi][2 + ni] = MFMA(Af[mi][1], Bf[2 + ni][1], acc[4 + mi][2 + ni]);
                }
            __builtin_amdgcn_s_setprio(0);
            if (kt < 15) {
                asm volatile("s_waitcnt vmcnt(6)" ::: "memory");
                __builtin_amdgcn_s_barrier();
                __builtin_amdgcn_sched_barrier(0);
            }
        }
        // ---------- sub-boundary epilogue (once per s, hoisted out of the kt loop)
        __builtin_amdgcn_s_barrier();           // close phase 3 of kt=15
        {
            const int row0_s = ((s << 6) + mtile0) << 8;
            const int bidx = row0_s >> 12;
            float hbv[4];
            #pragma unroll
            for (int ni = 0; ni < 4; ++ni) {
                int o = bidx * U_ + n0 + wn * 64 + ni * 16 + lm;
                hbv[ni] = hbp[o] + hbp[16384 + o] + hbp[32768 + o] + hbp[49152 + o];
            }
            #pragma unroll
            for (int mi = 0; mi < 8; ++mi) {
                #pragma unroll
                for (int r = 0; r < 4; ++r) {
                    float sc = 0.f;
                    #pragma unroll
                    for (int ni = 0; ni < 4; ++ni)
                        sc += fast_tanh(acc[mi][ni][r] + hbv[ni]) * Vv[ni];
                    #pragma unroll
                    for (int off = 1; off < 16; off <<= 1)
                        sc += __shfl_xor(sc, off, 64);
                    if (lm == 0)
                        sbuf[wn * 256 + wm * 128 + mi * 16 + quad * 4 + r] = sc;
                }
            }
            __syncthreads();
            if (tid < 256)
                scorepart[(size_t)nt * M_ + row0_s + tid] =
                    sbuf[tid] + sbuf[256 + tid] + sbuf[512 + tid] + sbuf[768 + tid];
            asm volatile("s_waitcnt vmcnt(0)" ::: "memory");   // drain store + next-sub stages
            __syncthreads();
            if (s < 3) {
                #pragma unroll
                for (int mi = 0; mi < 8; ++mi)
                    #pragma unroll
                    for (int ni = 0; ni < 4; ++ni)
                        acc[mi][ni] = (float4v){0.f, 0.f, 0.f, 0.f};
            }
        }
        aS += subStride;
    }
}

// ---------------- kernel 3: fused softmax + context partials.
__global__ __launch_bounds__(256) void ctx_softmax(
        const float* __restrict__ scorepart,
        const float* __restrict__ bv,
        const short* __restrict__ encbf,
        float* __restrict__ out_attn,
        float* __restrict__ part)    // [512][1024] (in dead W2T region)
{
    __shared__ float sm[T_];          // 16 KB
    __shared__ float wsm[128];
    __shared__ float lacc[1024];
    __shared__ float red[8];
    const int x = blockIdx.x, tid = threadIdx.x;   // 0..255
    const int b = x & 15, tc = x >> 4;
    const int wvi = tid >> 6;
    const float bv0 = bv[0];
    float lmax = -1e30f;
    #pragma unroll
    for (int i = 0; i < 16; ++i) {
        int t = tid + i * 256;
        const float* sp = scorepart + (size_t)b * T_ + t;
        float s = bv0 + sp[0] + sp[M_] + sp[2 * (size_t)M_] + sp[3 * (size_t)M_];
        sm[t] = s;
        lmax = fmaxf(lmax, s);
    }
    #pragma unroll
    for (int off = 1; off < 64; off <<= 1) lmax = fmaxf(lmax, __shfl_xor(lmax, off, 64));
    if ((tid & 63) == 0) red[wvi] = lmax;
    __syncthreads();
    const float m = fmaxf(fmaxf(red[0], red[1]), fmaxf(red[2], red[3]));
    float lsum = 0.f;
    #pragma unroll
    for (int i = 0; i < 16; ++i) lsum += __expf(sm[tid + i * 256] - m);
    #pragma unroll
    for (int off = 1; off < 64; off <<= 1) lsum += __shfl_xor(lsum, off, 64);
    if ((tid & 63) == 0) red[4 + wvi] = lsum;
    __syncthreads();
    const float tot = (red[4] + red[5]) + (red[6] + red[7]);
    const float rinv = 1.f / tot;
    // own 128 rows: attn out + LDS weights
    if ((tid >> 7) == (tc & 1)) {
        int j = tid & 127;
        int t = tc * 128 + j;
        float w = __expf(sm[t] - m) * rinv;
        wsm[j] = w;
        out_attn[b * T_ + t] = w;
    }
    __syncthreads();
    // weighted sum over 128 rows, 2 rows/iter (parity split), 16B loads
    const int par = tid >> 7;
    const int d0 = (tid & 127) * 8;
    const short* e0 = encbf + (size_t)(b * T_ + tc * 128 + par) * D_ + d0;
    float4v a0 = {}, a1 = {};
    #pragma unroll 4
    for (int it = 0; it < 64; ++it) {
        short8 v = *(const short8*)(e0 + (size_t)it * 2 * D_);
        float w = wsm[it * 2 + par];
        a0[0] += w * bf2f(v[0]); a0[1] += w * bf2f(v[1]);
        a0[2] += w * bf2f(v[2]); a0[3] += w * bf2f(v[3]);
        a1[0] += w * bf2f(v[4]); a1[1] += w * bf2f(v[5]);
        a1[2] += w * bf2f(v[6]); a1[3] += w * bf2f(v[7]);
    }
    if (par) {
        *(float4v*)(lacc + (tid & 127) * 8)     = a0;
        *(float4v*)(lacc + (tid & 127) * 8 + 4) = a1;
    }
    __syncthreads();
    if (!par) {
        const float* l = lacc + tid * 8;
        a0[0] += l[0]; a0[1] += l[1]; a0[2] += l[2]; a0[3] += l[3];
        a1[0] += l[4]; a1[1] += l[5]; a1[2] += l[6]; a1[3] += l[7];
        float4v* pp = (float4v*)(part + (size_t)x * 1024 + tid * 8);
        pp[0] = a0; pp[1] = a1;
    }
}

// ---------------- kernel 4: reduce context partials (32 per (b,d))
__global__ void ctx_reduce_kernel(const float* __restrict__ part, float* __restrict__ ctx) {
    int gid = blockIdx.x * 256 + threadIdx.x;   // 0..16383
    int b = gid >> 10, d = gid & 1023;
    float s = 0.f;
    #pragma unroll
    for (int tc = 0; tc < 32; ++tc) s += part[(size_t)(tc * 16 + b) * 1024 + d];
    ctx[gid] = s;
}

extern "C" void kernel_launch(void* const* d_in, const int* in_sizes, int n_in,
                              void* d_out, int out_size, void* d_ws, size_t ws_size,
                              hipStream_t stream) {
    const float* h   = (const float*)d_in[0];
    const float* enc = (const float*)d_in[1];
    const float* W1  = (const float*)d_in[2];
    const float* b1  = (const float*)d_in[3];
    const float* W2  = (const float*)d_in[4];
    const float* b2  = (const float*)d_in[5];
    const float* V   = (const float*)d_in[6];
    const float* bv  = (const float*)d_in[7];
    float* out = (float*)d_out;                 // [0,16384) context, [16384,81920) attn
    float* ws  = (float*)d_ws;

    float* hbp       = ws;                      // 4*16384 floats (256 KB)
    float* scorepart = ws + 65536;              // [4][M_] floats (1 MB of 2 MB slot)
    short* W2T   = (short*)(ws + 65536 + 524288);          // 2 MB
    float* ctxpart   = (float*)W2T;             // ALIAS: W2T dead after gemm; scorepart stays live
    short* encbf = (short*)((char*)W2T + (size_t)U_ * D_ * 2);  // 128 MB

    prep_fused<<<16896, 256, 0, stream>>>(h, W1, b1, b2, W2, enc, hbp, W2T, encbf);
    gemm_score_8ph<<<256, 512, 0, stream>>>(encbf, W2T, hbp, V, scorepart);
    ctx_softmax<<<512, 256, 0, stream>>>(scorepart, bv, encbf, out + 16384, ctxpart);
    ctx_reduce_kernel<<<64, 256, 0, stream>>>(ctxpart, out);
}

// Round 5
// 576.471 us; speedup vs baseline: 1.0111x; 1.0111x over previous
//
#include <hip/hip_runtime.h>
#include <hip/hip_bf16.h>
#include <math.h>

#define B_ 16
#define T_ 4096
#define D_ 1024
#define U_ 1024
#define M_ (B_*T_)   // 65536

typedef __attribute__((ext_vector_type(8))) short short8;
typedef __attribute__((ext_vector_type(4))) short short4v;
typedef __attribute__((ext_vector_type(4))) float float4v;

static __device__ __forceinline__ short f2bf(float f) {
    unsigned u = __builtin_bit_cast(unsigned, f);
    u += 0x7FFFu + ((u >> 16) & 1u);   // RNE
    return (short)(u >> 16);
}
static __device__ __forceinline__ float bf2f(short s) {
    unsigned u = ((unsigned)(unsigned short)s) << 16;
    return __builtin_bit_cast(float, u);
}
static __device__ __forceinline__ float fast_tanh(float x) {
    float c = fminf(fmaxf(2.f * x, -30.f), 30.f);
    float t = __expf(c);
    return __fdividef(t - 1.f, t + 1.f);
}

#define GLLDS(GP, LP) __builtin_amdgcn_global_load_lds( \
    (const __attribute__((address_space(1))) void*)(GP), \
    (__attribute__((address_space(3))) void*)(LP), 16, 0, 0)

// ---------------- kernel 1 (fused prep): hb partials + W2 transpose/convert + enc convert
// blocks [0,256): hb, [256,512): w2t, [512,2560): enc grid-stride.
// enc convert is LANE-CONTIGUOUS: each thread loads one float4 (dense 1KB/instr)
// and stores one short4 (dense 512B/instr), grid-stride over 16M float4s.
__global__ void prep_fused(const float* __restrict__ h, const float* __restrict__ W1,
                           const float* __restrict__ b1, const float* __restrict__ b2,
                           const float* __restrict__ W2, const float* __restrict__ enc,
                           float* __restrict__ hbp, short* __restrict__ W2T,
                           short* __restrict__ encbf) {
    int bx = blockIdx.x;
    if (bx >= 512) {
        // ---- convert_enc, coalesced grid-stride
        const float4v* __restrict__ in4 = (const float4v*)enc;
        short4v* __restrict__ out4 = (short4v*)encbf;
        const int N4 = (M_ * D_) / 4;            // 16777216
        const int stride = 2048 * 256;           // 524288
        int i = (bx - 512) * 256 + threadIdx.x;
        #pragma unroll 4
        for (; i < N4; i += stride) {
            float4v f = in4[i];
            short4v o;
            o[0] = f2bf(f[0]); o[1] = f2bf(f[1]);
            o[2] = f2bf(f[2]); o[3] = f2bf(f[3]);
            out4[i] = o;
        }
    } else if (bx < 256) {
        // ---- hb partials, K split 4 ways
        int kc = bx >> 6;
        int gid = (bx & 63) * 256 + threadIdx.x;
        int b = gid >> 10, u = gid & 1023;
        const float* hr = h + b * D_ + kc * 256;
        const float* w = W1 + (size_t)(kc * 256) * U_ + u;
        float s0 = 0.f, s1 = 0.f, s2 = 0.f, s3 = 0.f;
        for (int k = 0; k < 256; k += 4) {
            s0 += hr[k+0] * w[(size_t)(k+0) * U_];
            s1 += hr[k+1] * w[(size_t)(k+1) * U_];
            s2 += hr[k+2] * w[(size_t)(k+2) * U_];
            s3 += hr[k+3] * w[(size_t)(k+3) * U_];
        }
        float s = ((s0 + s1) + (s2 + s3));
        if (kc == 0) s += b1[u] + b2[u];
        hbp[kc * 16384 + gid] = s;
    } else {
        // ---- convert_w2t (transpose to [U][D])
        __shared__ short t[64][65];
        int x = bx - 256;
        int k0 = (x >> 4) * 64, u0 = (x & 15) * 64;
        int tx = threadIdx.x & 63, ty = threadIdx.x >> 6;
        #pragma unroll
        for (int r = 0; r < 16; ++r) {
            int kk = ty * 16 + r;
            t[kk][tx] = f2bf(W2[(size_t)(k0 + kk) * U_ + u0 + tx]);
        }
        __syncthreads();
        #pragma unroll
        for (int r = 0; r < 16; ++r) {
            int uu = ty * 16 + r;
            W2T[(size_t)(u0 + uu) * D_ + k0 + tx] = t[tx][uu];
        }
    }
}

// ---------------- kernel 2: 256x256-tile 8-phase bf16 GEMM + tanh*V epilogue.
// VERBATIM round-1/3 kernel (verified 180.8us twice) -- grid 1024, restart per tile.
__global__ __launch_bounds__(512, 2) void gemm_score_8ph(
    const short* __restrict__ Abf,   // enc bf16 [M_, D_]
    const short* __restrict__ W2T,   // bf16 [U_, D_]
    const float* __restrict__ hbp,   // [4][B_, U_]
    const float* __restrict__ V,
    float* __restrict__ scorepart)   // [4][M_]
{
    __shared__ __align__(16) short lds[65536];   // A: [0,32768), B: [32768,65536) shorts

    const int tid = threadIdx.x;
    const int g = blockIdx.x;
    const int c = g & 7, q = g >> 3;            // XCD round-robin; 1024 % 8 == 0 -> bijective
    const int ntile = q & 3;                    // 4 ntiles walked consecutively per XCD
    const int mtile = (q >> 2) * 8 + c;
    const int row0 = mtile * 256, n0 = ntile * 256;
    const int bidx = row0 >> 12;                // 256-row tile never crosses batch (4096 % 256 == 0)

    const int lane = tid & 63;
    const int wv = tid >> 6;
    const int wm = wv >> 2, wn = wv & 3;        // 2M x 4N waves
    const int lm = lane & 15, quad = lane >> 4;

    // staging geometry: one GLLDS round = 512 thr x 16B = 64 rows x 128B
    const int srow = tid >> 3;                  // row within 64-row round
    const int lslot = (tid & 7) ^ (srow & 7);   // inverse swizzle on the GLOBAL source
    const short* aS = Abf + (size_t)(row0 + srow) * D_ + lslot * 8;
    const short* bS = W2T + (size_t)(n0  + srow) * D_ + lslot * 8;
    short* aD = lds + tid * 8;                  // linear LDS dest (wave-uniform base + lane*16)
    short* bD = lds + 32768 + tid * 8;

#define STG_A(kt, h, bf) do { \
    GLLDS(aS + (size_t)((h) * 128) * D_ + (kt) * 64,      aD + (bf) * 16384 + (h) * 8192); \
    GLLDS(aS + (size_t)((h) * 128 + 64) * D_ + (kt) * 64, aD + (bf) * 16384 + (h) * 8192 + 4096); \
} while (0)
#define STG_B(kt, h, bf) do { \
    GLLDS(bS + (size_t)((h) * 128) * D_ + (kt) * 64,      bD + (bf) * 16384 + (h) * 8192); \
    GLLDS(bS + (size_t)((h) * 128 + 64) * D_ + (kt) * 64, bD + (bf) * 16384 + (h) * 8192 + 4096); \
} while (0)
#define LDS_RD(off) (*(const short8*)(lds + (off)))
#define MFMA(a, b, c) __builtin_amdgcn_mfma_f32_16x16x32_bf16((a), (b), (c), 0, 0, 0)

    // swizzled read bases: phys_slot = (ks*4+quad) ^ (lm&7); ks=1 flips bit 32 (shorts)
    const int aB0 = (wm * 128 + lm) * 64 + (quad ^ (lm & 7)) * 8;
    const int aB1 = aB0 ^ 32;
    const int bB0 = 32768 + (wn * 64 + lm) * 64 + (quad ^ (lm & 7)) * 8;
    const int bB1 = bB0 ^ 32;

    float4v acc[8][4] = {};
    short8 Af[4][2], Bf[4][2];

    // ---- prologue: tile0 all 4 halves, then tile1 {B-lo, A-lo, B-hi} (3 halves = 6 loads in flight)
    STG_A(0, 0, 0); STG_A(0, 1, 0); STG_B(0, 0, 0); STG_B(0, 1, 0);
    STG_B(1, 0, 1); STG_A(1, 0, 1); STG_B(1, 1, 1);
    asm volatile("s_waitcnt vmcnt(6)" ::: "memory");
    __builtin_amdgcn_s_barrier();
    __builtin_amdgcn_sched_barrier(0);

    for (int t = 0; t < 16; ++t) {
        const int buf = t & 1;
        const int ab = buf * 16384;
        // ---------- phase 0: read A-lo frags + B-lo frags (12 ds_read), stage A-hi(t+1)
        #pragma unroll
        for (int mi = 0; mi < 4; ++mi) {
            Af[mi][0] = LDS_RD(ab + aB0 + mi * 1024);
            Af[mi][1] = LDS_RD(ab + aB1 + mi * 1024);
        }
        #pragma unroll
        for (int ni = 0; ni < 2; ++ni) {
            Bf[ni][0] = LDS_RD(ab + bB0 + ni * 1024);
            Bf[ni][1] = LDS_RD(ab + bB1 + ni * 1024);
        }
        if (t < 15) STG_A(t + 1, 1, (t + 1) & 1);
        __builtin_amdgcn_s_barrier();
        __builtin_amdgcn_s_setprio(1);
        #pragma unroll
        for (int mi = 0; mi < 4; ++mi)
            #pragma unroll
            for (int ni = 0; ni < 2; ++ni) {
                acc[mi][ni] = MFMA(Af[mi][0], Bf[ni][0], acc[mi][ni]);
                acc[mi][ni] = MFMA(Af[mi][1], Bf[ni][1], acc[mi][ni]);
            }
        __builtin_amdgcn_s_setprio(0);
        __builtin_amdgcn_s_barrier();
        // ---------- phase 1: read B-hi frags (4 ds_read); B fully consumed after this phase
        #pragma unroll
        for (int ni = 0; ni < 2; ++ni) {
            Bf[2 + ni][0] = LDS_RD(ab + bB0 + (2 + ni) * 1024);
            Bf[2 + ni][1] = LDS_RD(ab + bB1 + (2 + ni) * 1024);
        }
        __builtin_amdgcn_s_barrier();
        __builtin_amdgcn_s_setprio(1);
        #pragma unroll
        for (int mi = 0; mi < 4; ++mi)
            #pragma unroll
            for (int ni = 0; ni < 2; ++ni) {
                acc[mi][2 + ni] = MFMA(Af[mi][0], Bf[2 + ni][0], acc[mi][2 + ni]);
                acc[mi][2 + ni] = MFMA(Af[mi][1], Bf[2 + ni][1], acc[mi][2 + ni]);
            }
        __builtin_amdgcn_s_setprio(0);
        __builtin_amdgcn_s_barrier();
        // ---------- phase 2: read A-hi frags (8 ds_read; A consumed after), stage B-lo(t+2)
        #pragma unroll
        for (int mi = 0; mi < 4; ++mi) {
            Af[mi][0] = LDS_RD(ab + aB0 + 4096 + mi * 1024);
            Af[mi][1] = LDS_RD(ab + aB1 + 4096 + mi * 1024);
        }
        if (t < 14) STG_B(t + 2, 0, buf);
        __builtin_amdgcn_s_barrier();
        __builtin_amdgcn_s_setprio(1);
        #pragma unroll
        for (int mi = 0; mi < 4; ++mi)
            #pragma unroll
            for (int ni = 0; ni < 2; ++ni) {
                acc[4 + mi][ni] = MFMA(Af[mi][0], Bf[ni][0], acc[4 + mi][ni]);
                acc[4 + mi][ni] = MFMA(Af[mi][1], Bf[ni][1], acc[4 + mi][ni]);
            }
        __builtin_amdgcn_s_setprio(0);
        __builtin_amdgcn_s_barrier();
        // ---------- phase 3: no reads; stage A-lo(t+2)+B-hi(t+2); counted vmcnt at tile boundary
        if (t < 14) { STG_A(t + 2, 0, buf); STG_B(t + 2, 1, buf); }
        __builtin_amdgcn_s_barrier();
        __builtin_amdgcn_s_setprio(1);
        #pragma unroll
        for (int mi = 0; mi < 4; ++mi)
            #pragma unroll
            for (int ni = 0; ni < 2; ++ni) {
                acc[4 + mi][2 + ni] = MFMA(Af[mi][0], Bf[2 + ni][0], acc[4 + mi][2 + ni]);
                acc[4 + mi][2 + ni] = MFMA(Af[mi][1], Bf[2 + ni][1], acc[4 + mi][2 + ni]);
            }
        __builtin_amdgcn_s_setprio(0);
        if (t < 14)      { asm volatile("s_waitcnt vmcnt(6)" ::: "memory"); }
        else if (t == 14){ asm volatile("s_waitcnt vmcnt(0)" ::: "memory"); }
        __builtin_amdgcn_s_barrier();
        __builtin_amdgcn_sched_barrier(0);
    }

    // ---------- epilogue: score = sum_u tanh(acc + hb) * V over this block's 256 u's
    float* sbuf = (float*)lds;                  // [4][256] floats; LDS reads all drained
    float hbv[4], Vv[4];
    #pragma unroll
    for (int ni = 0; ni < 4; ++ni) {
        int U = n0 + wn * 64 + ni * 16 + lm;
        int o = bidx * U_ + U;
        hbv[ni] = hbp[o] + hbp[16384 + o] + hbp[32768 + o] + hbp[49152 + o];
        Vv[ni]  = V[U];
    }
    #pragma unroll
    for (int mi = 0; mi < 8; ++mi) {
        #pragma unroll
        for (int r = 0; r < 4; ++r) {
            float s = 0.f;
            #pragma unroll
            for (int ni = 0; ni < 4; ++ni)
                s += fast_tanh(acc[mi][ni][r] + hbv[ni]) * Vv[ni];
            #pragma unroll
            for (int off = 1; off < 16; off <<= 1)
                s += __shfl_xor(s, off, 64);
            if (lm == 0)
                sbuf[wn * 256 + wm * 128 + mi * 16 + quad * 4 + r] = s;
        }
    }
    __syncthreads();
    if (tid < 256)
        scorepart[(size_t)ntile * M_ + row0 + tid] =
            sbuf[tid] + sbuf[256 + tid] + sbuf[512 + tid] + sbuf[768 + tid];
}

// ---------------- kernel 3: fused softmax + context partials (verbatim round-3).
__global__ __launch_bounds__(256) void ctx_softmax(
        const float* __restrict__ scorepart,
        const float* __restrict__ bv,
        const short* __restrict__ encbf,
        float* __restrict__ out_attn,
        float* __restrict__ part)    // [512][1024] (in dead W2T region)
{
    __shared__ float sm[T_];          // 16 KB
    __shared__ float wsm[128];
    __shared__ float lacc[1024];
    __shared__ float red[8];
    const int x = blockIdx.x, tid = threadIdx.x;   // 0..255
    const int b = x & 15, tc = x >> 4;
    const int wvi = tid >> 6;
    const float bv0 = bv[0];
    float lmax = -1e30f;
    #pragma unroll
    for (int i = 0; i < 16; ++i) {
        int t = tid + i * 256;
        const float* sp = scorepart + (size_t)b * T_ + t;
        float s = bv0 + sp[0] + sp[M_] + sp[2 * (size_t)M_] + sp[3 * (size_t)M_];
        sm[t] = s;
        lmax = fmaxf(lmax, s);
    }
    #pragma unroll
    for (int off = 1; off < 64; off <<= 1) lmax = fmaxf(lmax, __shfl_xor(lmax, off, 64));
    if ((tid & 63) == 0) red[wvi] = lmax;
    __syncthreads();
    const float m = fmaxf(fmaxf(red[0], red[1]), fmaxf(red[2], red[3]));
    float lsum = 0.f;
    #pragma unroll
    for (int i = 0; i < 16; ++i) lsum += __expf(sm[tid + i * 256] - m);
    #pragma unroll
    for (int off = 1; off < 64; off <<= 1) lsum += __shfl_xor(lsum, off, 64);
    if ((tid & 63) == 0) red[4 + wvi] = lsum;
    __syncthreads();
    const float tot = (red[4] + red[5]) + (red[6] + red[7]);
    const float rinv = 1.f / tot;
    // own 128 rows: attn out + LDS weights
    if ((tid >> 7) == (tc & 1)) {
        int j = tid & 127;
        int t = tc * 128 + j;
        float w = __expf(sm[t] - m) * rinv;
        wsm[j] = w;
        out_attn[b * T_ + t] = w;
    }
    __syncthreads();
    // weighted sum over 128 rows, 2 rows/iter (parity split), 16B loads
    const int par = tid >> 7;
    const int d0 = (tid & 127) * 8;
    const short* e0 = encbf + (size_t)(b * T_ + tc * 128 + par) * D_ + d0;
    float4v a0 = {}, a1 = {};
    #pragma unroll 4
    for (int it = 0; it < 64; ++it) {
        short8 v = *(const short8*)(e0 + (size_t)it * 2 * D_);
        float w = wsm[it * 2 + par];
        a0[0] += w * bf2f(v[0]); a0[1] += w * bf2f(v[1]);
        a0[2] += w * bf2f(v[2]); a0[3] += w * bf2f(v[3]);
        a1[0] += w * bf2f(v[4]); a1[1] += w * bf2f(v[5]);
        a1[2] += w * bf2f(v[6]); a1[3] += w * bf2f(v[7]);
    }
    if (par) {
        *(float4v*)(lacc + (tid & 127) * 8)     = a0;
        *(float4v*)(lacc + (tid & 127) * 8 + 4) = a1;
    }
    __syncthreads();
    if (!par) {
        const float* l = lacc + tid * 8;
        a0[0] += l[0]; a0[1] += l[1]; a0[2] += l[2]; a0[3] += l[3];
        a1[0] += l[4]; a1[1] += l[5]; a1[2] += l[6]; a1[3] += l[7];
        float4v* pp = (float4v*)(part + (size_t)x * 1024 + tid * 8);
        pp[0] = a0; pp[1] = a1;
    }
}

// ---------------- kernel 4: reduce context partials (32 per (b,d)), float4-vectorized
__global__ void ctx_reduce_kernel(const float* __restrict__ part, float* __restrict__ ctx) {
    int gid = blockIdx.x * 256 + threadIdx.x;   // 0..4095, one float4 each
    int b = gid >> 8, d4 = gid & 255;
    float4v s = {};
    #pragma unroll
    for (int tc = 0; tc < 32; ++tc) {
        float4v v = *(const float4v*)(part + (size_t)(tc * 16 + b) * 1024 + d4 * 4);
        s[0] += v[0]; s[1] += v[1]; s[2] += v[2]; s[3] += v[3];
    }
    *(float4v*)(ctx + (size_t)b * 1024 + d4 * 4) = s;
}

extern "C" void kernel_launch(void* const* d_in, const int* in_sizes, int n_in,
                              void* d_out, int out_size, void* d_ws, size_t ws_size,
                              hipStream_t stream) {
    const float* h   = (const float*)d_in[0];
    const float* enc = (const float*)d_in[1];
    const float* W1  = (const float*)d_in[2];
    const float* b1  = (const float*)d_in[3];
    const float* W2  = (const float*)d_in[4];
    const float* b2  = (const float*)d_in[5];
    const float* V   = (const float*)d_in[6];
    const float* bv  = (const float*)d_in[7];
    float* out = (float*)d_out;                 // [0,16384) context, [16384,81920) attn
    float* ws  = (float*)d_ws;

    float* hbp       = ws;                      // 4*16384 floats (256 KB)
    float* scorepart = ws + 65536;              // [4][M_] floats (1 MB of 2 MB slot)
    short* W2T   = (short*)(ws + 65536 + 524288);          // 2 MB
    float* ctxpart   = (float*)W2T;             // ALIAS: W2T dead after gemm; scorepart stays live
    short* encbf = (short*)((char*)W2T + (size_t)U_ * D_ * 2);  // 128 MB

    prep_fused<<<2560, 256, 0, stream>>>(h, W1, b1, b2, W2, enc, hbp, W2T, encbf);
    gemm_score_8ph<<<1024, 512, 0, stream>>>(encbf, W2T, hbp, V, scorepart);
    ctx_softmax<<<512, 256, 0, stream>>>(scorepart, bv, encbf, out + 16384, ctxpart);
    ctx_reduce_kernel<<<16, 256, 0, stream>>>(ctxpart, out);
}

// Round 6
// 562.774 us; speedup vs baseline: 1.0357x; 1.0243x over previous
//
#include <hip/hip_runtime.h>
#include <hip/hip_bf16.h>
#include <math.h>

#define B_ 16
#define T_ 4096
#define D_ 1024
#define U_ 1024
#define M_ (B_*T_)   // 65536

typedef __attribute__((ext_vector_type(8))) short short8;
typedef __attribute__((ext_vector_type(4))) short short4v;
typedef __attribute__((ext_vector_type(4))) float float4v;

static __device__ __forceinline__ short f2bf(float f) {
    unsigned u = __builtin_bit_cast(unsigned, f);
    u += 0x7FFFu + ((u >> 16) & 1u);   // RNE
    return (short)(u >> 16);
}
static __device__ __forceinline__ float bf2f(short s) {
    unsigned u = ((unsigned)(unsigned short)s) << 16;
    return __builtin_bit_cast(float, u);
}
static __device__ __forceinline__ float fast_tanh(float x) {
    float c = fminf(fmaxf(2.f * x, -30.f), 30.f);
    float t = __expf(c);
    return __fdividef(t - 1.f, t + 1.f);
}

#define GLLDS(GP, LP) __builtin_amdgcn_global_load_lds( \
    (const __attribute__((address_space(1))) void*)(GP), \
    (__attribute__((address_space(3))) void*)(LP), 16, 0, 0)

// ---------------- kernel 1 (fused prep): hb partials + W2 transpose/convert + enc convert
// VERBATIM round-3 version (best measured "rest"): blocks [0,256): hb,
// [256,512): w2t, [512,16896): enc with thread-owns-64B linear streaming.
__global__ void prep_fused(const float* __restrict__ h, const float* __restrict__ W1,
                           const float* __restrict__ b1, const float* __restrict__ b2,
                           const float* __restrict__ W2, const float* __restrict__ enc,
                           float* __restrict__ hbp, short* __restrict__ W2T,
                           short* __restrict__ encbf) {
    int bx = blockIdx.x;
    if (bx >= 512) {
        // ---- convert_enc
        size_t g = (size_t)(bx - 512) * 256 + threadIdx.x;
        const float4v* p = (const float4v*)(enc + g * 16);
        float4v f0 = p[0], f1 = p[1], f2 = p[2], f3 = p[3];
        short8 a, b;
        a[0]=f2bf(f0[0]); a[1]=f2bf(f0[1]); a[2]=f2bf(f0[2]); a[3]=f2bf(f0[3]);
        a[4]=f2bf(f1[0]); a[5]=f2bf(f1[1]); a[6]=f2bf(f1[2]); a[7]=f2bf(f1[3]);
        b[0]=f2bf(f2[0]); b[1]=f2bf(f2[1]); b[2]=f2bf(f2[2]); b[3]=f2bf(f2[3]);
        b[4]=f2bf(f3[0]); b[5]=f2bf(f3[1]); b[6]=f2bf(f3[2]); b[7]=f2bf(f3[3]);
        short8* q = (short8*)(encbf + g * 16);
        q[0] = a; q[1] = b;
    } else if (bx < 256) {
        // ---- hb partials, K split 4 ways
        int kc = bx >> 6;
        int gid = (bx & 63) * 256 + threadIdx.x;
        int b = gid >> 10, u = gid & 1023;
        const float* hr = h + b * D_ + kc * 256;
        const float* w = W1 + (size_t)(kc * 256) * U_ + u;
        float s0 = 0.f, s1 = 0.f, s2 = 0.f, s3 = 0.f;
        for (int k = 0; k < 256; k += 4) {
            s0 += hr[k+0] * w[(size_t)(k+0) * U_];
            s1 += hr[k+1] * w[(size_t)(k+1) * U_];
            s2 += hr[k+2] * w[(size_t)(k+2) * U_];
            s3 += hr[k+3] * w[(size_t)(k+3) * U_];
        }
        float s = ((s0 + s1) + (s2 + s3));
        if (kc == 0) s += b1[u] + b2[u];
        hbp[kc * 16384 + gid] = s;
    } else {
        // ---- convert_w2t (transpose to [U][D])
        __shared__ short t[64][65];
        int x = bx - 256;
        int k0 = (x >> 4) * 64, u0 = (x & 15) * 64;
        int tx = threadIdx.x & 63, ty = threadIdx.x >> 6;
        #pragma unroll
        for (int r = 0; r < 16; ++r) {
            int kk = ty * 16 + r;
            t[kk][tx] = f2bf(W2[(size_t)(k0 + kk) * U_ + u0 + tx]);
        }
        __syncthreads();
        #pragma unroll
        for (int r = 0; r < 16; ++r) {
            int uu = ty * 16 + r;
            W2T[(size_t)(u0 + uu) * D_ + k0 + tx] = t[tx][uu];
        }
    }
}

// ---------------- kernel 2: 256x256-tile 8-phase bf16 GEMM + tanh*V epilogue.
// VERBATIM round-1/3 kernel except: g = blockIdx.x + bofs. Launched TWICE with grid
// 512 (bofs 0 / 512) -> two ~90us dispatches. DIAGNOSTIC: lowers the top-5 visibility
// threshold from ~179us to ~90us so the hidden non-gemm time surfaces in the census.
__global__ __launch_bounds__(512, 2) void gemm_score_8ph(
    const short* __restrict__ Abf,   // enc bf16 [M_, D_]
    const short* __restrict__ W2T,   // bf16 [U_, D_]
    const float* __restrict__ hbp,   // [4][B_, U_]
    const float* __restrict__ V,
    float* __restrict__ scorepart,   // [4][M_]
    int bofs)
{
    __shared__ __align__(16) short lds[65536];   // A: [0,32768), B: [32768,65536) shorts

    const int tid = threadIdx.x;
    const int g = blockIdx.x + bofs;
    const int c = g & 7, q = g >> 3;            // XCD round-robin
    const int ntile = q & 3;                    // 4 ntiles walked consecutively per XCD
    const int mtile = (q >> 2) * 8 + c;
    const int row0 = mtile * 256, n0 = ntile * 256;
    const int bidx = row0 >> 12;                // 256-row tile never crosses batch (4096 % 256 == 0)

    const int lane = tid & 63;
    const int wv = tid >> 6;
    const int wm = wv >> 2, wn = wv & 3;        // 2M x 4N waves
    const int lm = lane & 15, quad = lane >> 4;

    // staging geometry: one GLLDS round = 512 thr x 16B = 64 rows x 128B
    const int srow = tid >> 3;                  // row within 64-row round
    const int lslot = (tid & 7) ^ (srow & 7);   // inverse swizzle on the GLOBAL source
    const short* aS = Abf + (size_t)(row0 + srow) * D_ + lslot * 8;
    const short* bS = W2T + (size_t)(n0  + srow) * D_ + lslot * 8;
    short* aD = lds + tid * 8;                  // linear LDS dest (wave-uniform base + lane*16)
    short* bD = lds + 32768 + tid * 8;

#define STG_A(kt, h, bf) do { \
    GLLDS(aS + (size_t)((h) * 128) * D_ + (kt) * 64,      aD + (bf) * 16384 + (h) * 8192); \
    GLLDS(aS + (size_t)((h) * 128 + 64) * D_ + (kt) * 64, aD + (bf) * 16384 + (h) * 8192 + 4096); \
} while (0)
#define STG_B(kt, h, bf) do { \
    GLLDS(bS + (size_t)((h) * 128) * D_ + (kt) * 64,      bD + (bf) * 16384 + (h) * 8192); \
    GLLDS(bS + (size_t)((h) * 128 + 64) * D_ + (kt) * 64, bD + (bf) * 16384 + (h) * 8192 + 4096); \
} while (0)
#define LDS_RD(off) (*(const short8*)(lds + (off)))
#define MFMA(a, b, c) __builtin_amdgcn_mfma_f32_16x16x32_bf16((a), (b), (c), 0, 0, 0)

    // swizzled read bases: phys_slot = (ks*4+quad) ^ (lm&7); ks=1 flips bit 32 (shorts)
    const int aB0 = (wm * 128 + lm) * 64 + (quad ^ (lm & 7)) * 8;
    const int aB1 = aB0 ^ 32;
    const int bB0 = 32768 + (wn * 64 + lm) * 64 + (quad ^ (lm & 7)) * 8;
    const int bB1 = bB0 ^ 32;

    float4v acc[8][4] = {};
    short8 Af[4][2], Bf[4][2];

    // ---- prologue: tile0 all 4 halves, then tile1 {B-lo, A-lo, B-hi} (3 halves = 6 loads in flight)
    STG_A(0, 0, 0); STG_A(0, 1, 0); STG_B(0, 0, 0); STG_B(0, 1, 0);
    STG_B(1, 0, 1); STG_A(1, 0, 1); STG_B(1, 1, 1);
    asm volatile("s_waitcnt vmcnt(6)" ::: "memory");
    __builtin_amdgcn_s_barrier();
    __builtin_amdgcn_sched_barrier(0);

    for (int t = 0; t < 16; ++t) {
        const int buf = t & 1;
        const int ab = buf * 16384;
        // ---------- phase 0: read A-lo frags + B-lo frags (12 ds_read), stage A-hi(t+1)
        #pragma unroll
        for (int mi = 0; mi < 4; ++mi) {
            Af[mi][0] = LDS_RD(ab + aB0 + mi * 1024);
            Af[mi][1] = LDS_RD(ab + aB1 + mi * 1024);
        }
        #pragma unroll
        for (int ni = 0; ni < 2; ++ni) {
            Bf[ni][0] = LDS_RD(ab + bB0 + ni * 1024);
            Bf[ni][1] = LDS_RD(ab + bB1 + ni * 1024);
        }
        if (t < 15) STG_A(t + 1, 1, (t + 1) & 1);
        __builtin_amdgcn_s_barrier();
        __builtin_amdgcn_s_setprio(1);
        #pragma unroll
        for (int mi = 0; mi < 4; ++mi)
            #pragma unroll
            for (int ni = 0; ni < 2; ++ni) {
                acc[mi][ni] = MFMA(Af[mi][0], Bf[ni][0], acc[mi][ni]);
                acc[mi][ni] = MFMA(Af[mi][1], Bf[ni][1], acc[mi][ni]);
            }
        __builtin_amdgcn_s_setprio(0);
        __builtin_amdgcn_s_barrier();
        // ---------- phase 1: read B-hi frags (4 ds_read); B fully consumed after this phase
        #pragma unroll
        for (int ni = 0; ni < 2; ++ni) {
            Bf[2 + ni][0] = LDS_RD(ab + bB0 + (2 + ni) * 1024);
            Bf[2 + ni][1] = LDS_RD(ab + bB1 + (2 + ni) * 1024);
        }
        __builtin_amdgcn_s_barrier();
        __builtin_amdgcn_s_setprio(1);
        #pragma unroll
        for (int mi = 0; mi < 4; ++mi)
            #pragma unroll
            for (int ni = 0; ni < 2; ++ni) {
                acc[mi][2 + ni] = MFMA(Af[mi][0], Bf[2 + ni][0], acc[mi][2 + ni]);
                acc[mi][2 + ni] = MFMA(Af[mi][1], Bf[2 + ni][1], acc[mi][2 + ni]);
            }
        __builtin_amdgcn_s_setprio(0);
        __builtin_amdgcn_s_barrier();
        // ---------- phase 2: read A-hi frags (8 ds_read; A consumed after), stage B-lo(t+2)
        #pragma unroll
        for (int mi = 0; mi < 4; ++mi) {
            Af[mi][0] = LDS_RD(ab + aB0 + 4096 + mi * 1024);
            Af[mi][1] = LDS_RD(ab + aB1 + 4096 + mi * 1024);
        }
        if (t < 14) STG_B(t + 2, 0, buf);
        __builtin_amdgcn_s_barrier();
        __builtin_amdgcn_s_setprio(1);
        #pragma unroll
        for (int mi = 0; mi < 4; ++mi)
            #pragma unroll
            for (int ni = 0; ni < 2; ++ni) {
                acc[4 + mi][ni] = MFMA(Af[mi][0], Bf[ni][0], acc[4 + mi][ni]);
                acc[4 + mi][ni] = MFMA(Af[mi][1], Bf[ni][1], acc[4 + mi][ni]);
            }
        __builtin_amdgcn_s_setprio(0);
        __builtin_amdgcn_s_barrier();
        // ---------- phase 3: no reads; stage A-lo(t+2)+B-hi(t+2); counted vmcnt at tile boundary
        if (t < 14) { STG_A(t + 2, 0, buf); STG_B(t + 2, 1, buf); }
        __builtin_amdgcn_s_barrier();
        __builtin_amdgcn_s_setprio(1);
        #pragma unroll
        for (int mi = 0; mi < 4; ++mi)
            #pragma unroll
            for (int ni = 0; ni < 2; ++ni) {
                acc[4 + mi][2 + ni] = MFMA(Af[mi][0], Bf[2 + ni][0], acc[4 + mi][2 + ni]);
                acc[4 + mi][2 + ni] = MFMA(Af[mi][1], Bf[2 + ni][1], acc[4 + mi][2 + ni]);
            }
        __builtin_amdgcn_s_setprio(0);
        if (t < 14)      { asm volatile("s_waitcnt vmcnt(6)" ::: "memory"); }
        else if (t == 14){ asm volatile("s_waitcnt vmcnt(0)" ::: "memory"); }
        __builtin_amdgcn_s_barrier();
        __builtin_amdgcn_sched_barrier(0);
    }

    // ---------- epilogue: score = sum_u tanh(acc + hb) * V over this block's 256 u's
    float* sbuf = (float*)lds;                  // [4][256] floats; LDS reads all drained
    float hbv[4], Vv[4];
    #pragma unroll
    for (int ni = 0; ni < 4; ++ni) {
        int U = n0 + wn * 64 + ni * 16 + lm;
        int o = bidx * U_ + U;
        hbv[ni] = hbp[o] + hbp[16384 + o] + hbp[32768 + o] + hbp[49152 + o];
        Vv[ni]  = V[U];
    }
    #pragma unroll
    for (int mi = 0; mi < 8; ++mi) {
        #pragma unroll
        for (int r = 0; r < 4; ++r) {
            float s = 0.f;
            #pragma unroll
            for (int ni = 0; ni < 4; ++ni)
                s += fast_tanh(acc[mi][ni][r] + hbv[ni]) * Vv[ni];
            #pragma unroll
            for (int off = 1; off < 16; off <<= 1)
                s += __shfl_xor(s, off, 64);
            if (lm == 0)
                sbuf[wn * 256 + wm * 128 + mi * 16 + quad * 4 + r] = s;
        }
    }
    __syncthreads();
    if (tid < 256)
        scorepart[(size_t)ntile * M_ + row0 + tid] =
            sbuf[tid] + sbuf[256 + tid] + sbuf[512 + tid] + sbuf[768 + tid];
}

// ---------------- kernel 3: fused softmax + context partials (verbatim round-3).
__global__ __launch_bounds__(256) void ctx_softmax(
        const float* __restrict__ scorepart,
        const float* __restrict__ bv,
        const short* __restrict__ encbf,
        float* __restrict__ out_attn,
        float* __restrict__ part)    // [512][1024] (in dead W2T region)
{
    __shared__ float sm[T_];          // 16 KB
    __shared__ float wsm[128];
    __shared__ float lacc[1024];
    __shared__ float red[8];
    const int x = blockIdx.x, tid = threadIdx.x;   // 0..255
    const int b = x & 15, tc = x >> 4;
    const int wvi = tid >> 6;
    const float bv0 = bv[0];
    float lmax = -1e30f;
    #pragma unroll
    for (int i = 0; i < 16; ++i) {
        int t = tid + i * 256;
        const float* sp = scorepart + (size_t)b * T_ + t;
        float s = bv0 + sp[0] + sp[M_] + sp[2 * (size_t)M_] + sp[3 * (size_t)M_];
        sm[t] = s;
        lmax = fmaxf(lmax, s);
    }
    #pragma unroll
    for (int off = 1; off < 64; off <<= 1) lmax = fmaxf(lmax, __shfl_xor(lmax, off, 64));
    if ((tid & 63) == 0) red[wvi] = lmax;
    __syncthreads();
    const float m = fmaxf(fmaxf(red[0], red[1]), fmaxf(red[2], red[3]));
    float lsum = 0.f;
    #pragma unroll
    for (int i = 0; i < 16; ++i) lsum += __expf(sm[tid + i * 256] - m);
    #pragma unroll
    for (int off = 1; off < 64; off <<= 1) lsum += __shfl_xor(lsum, off, 64);
    if ((tid & 63) == 0) red[4 + wvi] = lsum;
    __syncthreads();
    const float tot = (red[4] + red[5]) + (red[6] + red[7]);
    const float rinv = 1.f / tot;
    // own 128 rows: attn out + LDS weights
    if ((tid >> 7) == (tc & 1)) {
        int j = tid & 127;
        int t = tc * 128 + j;
        float w = __expf(sm[t] - m) * rinv;
        wsm[j] = w;
        out_attn[b * T_ + t] = w;
    }
    __syncthreads();
    // weighted sum over 128 rows, 2 rows/iter (parity split), 16B loads
    const int par = tid >> 7;
    const int d0 = (tid & 127) * 8;
    const short* e0 = encbf + (size_t)(b * T_ + tc * 128 + par) * D_ + d0;
    float4v a0 = {}, a1 = {};
    #pragma unroll 4
    for (int it = 0; it < 64; ++it) {
        short8 v = *(const short8*)(e0 + (size_t)it * 2 * D_);
        float w = wsm[it * 2 + par];
        a0[0] += w * bf2f(v[0]); a0[1] += w * bf2f(v[1]);
        a0[2] += w * bf2f(v[2]); a0[3] += w * bf2f(v[3]);
        a1[0] += w * bf2f(v[4]); a1[1] += w * bf2f(v[5]);
        a1[2] += w * bf2f(v[6]); a1[3] += w * bf2f(v[7]);
    }
    if (par) {
        *(float4v*)(lacc + (tid & 127) * 8)     = a0;
        *(float4v*)(lacc + (tid & 127) * 8 + 4) = a1;
    }
    __syncthreads();
    if (!par) {
        const float* l = lacc + tid * 8;
        a0[0] += l[0]; a0[1] += l[1]; a0[2] += l[2]; a0[3] += l[3];
        a1[0] += l[4]; a1[1] += l[5]; a1[2] += l[6]; a1[3] += l[7];
        float4v* pp = (float4v*)(part + (size_t)x * 1024 + tid * 8);
        pp[0] = a0; pp[1] = a1;
    }
}

// ---------------- kernel 4: reduce context partials (verbatim round-3)
__global__ void ctx_reduce_kernel(const float* __restrict__ part, float* __restrict__ ctx) {
    int gid = blockIdx.x * 256 + threadIdx.x;   // 0..16383
    int b = gid >> 10, d = gid & 1023;
    float s = 0.f;
    #pragma unroll
    for (int tc = 0; tc < 32; ++tc) s += part[(size_t)(tc * 16 + b) * 1024 + d];
    ctx[gid] = s;
}

extern "C" void kernel_launch(void* const* d_in, const int* in_sizes, int n_in,
                              void* d_out, int out_size, void* d_ws, size_t ws_size,
                              hipStream_t stream) {
    const float* h   = (const float*)d_in[0];
    const float* enc = (const float*)d_in[1];
    const float* W1  = (const float*)d_in[2];
    const float* b1  = (const float*)d_in[3];
    const float* W2  = (const float*)d_in[4];
    const float* b2  = (const float*)d_in[5];
    const float* V   = (const float*)d_in[6];
    const float* bv  = (const float*)d_in[7];
    float* out = (float*)d_out;                 // [0,16384) context, [16384,81920) attn
    float* ws  = (float*)d_ws;

    float* hbp       = ws;                      // 4*16384 floats (256 KB)
    float* scorepart = ws + 65536;              // [4][M_] floats (1 MB of 2 MB slot)
    short* W2T   = (short*)(ws + 65536 + 524288);          // 2 MB
    float* ctxpart   = (float*)W2T;             // ALIAS: W2T dead after gemm; scorepart stays live
    short* encbf = (short*)((char*)W2T + (size_t)U_ * D_ * 2);  // 128 MB

    prep_fused<<<16896, 256, 0, stream>>>(h, W1, b1, b2, W2, enc, hbp, W2T, encbf);
    gemm_score_8ph<<<512, 512, 0, stream>>>(encbf, W2T, hbp, V, scorepart, 0);
    gemm_score_8ph<<<512, 512, 0, stream>>>(encbf, W2T, hbp, V, scorepart, 512);
    ctx_softmax<<<512, 256, 0, stream>>>(scorepart, bv, encbf, out + 16384, ctxpart);
    ctx_reduce_kernel<<<64, 256, 0, stream>>>(ctxpart, out);
}

// Round 7
// 562.667 us; speedup vs baseline: 1.0359x; 1.0002x over previous
//
#include <hip/hip_runtime.h>
#include <hip/hip_bf16.h>
#include <math.h>

#define B_ 16
#define T_ 4096
#define D_ 1024
#define U_ 1024
#define M_ (B_*T_)   // 65536

typedef __attribute__((ext_vector_type(8))) short short8;
typedef __attribute__((ext_vector_type(4))) short short4v;
typedef __attribute__((ext_vector_type(4))) float float4v;

static __device__ __forceinline__ short f2bf(float f) {
    unsigned u = __builtin_bit_cast(unsigned, f);
    u += 0x7FFFu + ((u >> 16) & 1u);   // RNE
    return (short)(u >> 16);
}
static __device__ __forceinline__ float bf2f(short s) {
    unsigned u = ((unsigned)(unsigned short)s) << 16;
    return __builtin_bit_cast(float, u);
}
static __device__ __forceinline__ float fast_tanh(float x) {
    float c = fminf(fmaxf(2.f * x, -30.f), 30.f);
    float t = __expf(c);
    return __fdividef(t - 1.f, t + 1.f);
}

#define GLLDS(GP, LP) __builtin_amdgcn_global_load_lds( \
    (const __attribute__((address_space(1))) void*)(GP), \
    (__attribute__((address_space(3))) void*)(LP), 16, 0, 0)

// ---------------- kernel 1 (fused prep): hb partials + W2 transpose/convert + enc convert
// blocks [0,256): hb, [256,512): w2t, [512,16896): enc.
// enc branch: block j owns a 16KB window; thread t loads float4 j*1024+k*256+t
// (k=0..3) -> EVERY load instruction is 4KB dense across the block (lane-stride 16B,
// the coalescing ideal), stores 2KB dense. Same traffic/locality as round-3, dense issue.
__global__ void prep_fused(const float* __restrict__ h, const float* __restrict__ W1,
                           const float* __restrict__ b1, const float* __restrict__ b2,
                           const float* __restrict__ W2, const float* __restrict__ enc,
                           float* __restrict__ hbp, short* __restrict__ W2T,
                           short* __restrict__ encbf) {
    int bx = blockIdx.x;
    if (bx >= 512) {
        // ---- convert_enc, per-instruction-dense
        const float4v* __restrict__ in4 = (const float4v*)enc;
        short4v* __restrict__ out4 = (short4v*)encbf;
        const size_t base = (size_t)(bx - 512) * 1024 + threadIdx.x;
        #pragma unroll
        for (int k = 0; k < 4; ++k) {
            size_t i = base + k * 256;
            float4v f = in4[i];
            short4v o;
            o[0] = f2bf(f[0]); o[1] = f2bf(f[1]);
            o[2] = f2bf(f[2]); o[3] = f2bf(f[3]);
            out4[i] = o;
        }
    } else if (bx < 256) {
        // ---- hb partials, K split 4 ways
        int kc = bx >> 6;
        int gid = (bx & 63) * 256 + threadIdx.x;
        int b = gid >> 10, u = gid & 1023;
        const float* hr = h + b * D_ + kc * 256;
        const float* w = W1 + (size_t)(kc * 256) * U_ + u;
        float s0 = 0.f, s1 = 0.f, s2 = 0.f, s3 = 0.f;
        for (int k = 0; k < 256; k += 4) {
            s0 += hr[k+0] * w[(size_t)(k+0) * U_];
            s1 += hr[k+1] * w[(size_t)(k+1) * U_];
            s2 += hr[k+2] * w[(size_t)(k+2) * U_];
            s3 += hr[k+3] * w[(size_t)(k+3) * U_];
        }
        float s = ((s0 + s1) + (s2 + s3));
        if (kc == 0) s += b1[u] + b2[u];
        hbp[kc * 16384 + gid] = s;
    } else {
        // ---- convert_w2t (transpose to [U][D])
        __shared__ short t[64][65];
        int x = bx - 256;
        int k0 = (x >> 4) * 64, u0 = (x & 15) * 64;
        int tx = threadIdx.x & 63, ty = threadIdx.x >> 6;
        #pragma unroll
        for (int r = 0; r < 16; ++r) {
            int kk = ty * 16 + r;
            t[kk][tx] = f2bf(W2[(size_t)(k0 + kk) * U_ + u0 + tx]);
        }
        __syncthreads();
        #pragma unroll
        for (int r = 0; r < 16; ++r) {
            int uu = ty * 16 + r;
            W2T[(size_t)(u0 + uu) * D_ + k0 + tx] = t[tx][uu];
        }
    }
}

// ---------------- kernel 2: 256x256-tile 8-phase bf16 GEMM + tanh*V epilogue.
// VERBATIM verified kernel (180.8us x3) -- grid 1024 single dispatch (split reverted).
__global__ __launch_bounds__(512, 2) void gemm_score_8ph(
    const short* __restrict__ Abf,   // enc bf16 [M_, D_]
    const short* __restrict__ W2T,   // bf16 [U_, D_]
    const float* __restrict__ hbp,   // [4][B_, U_]
    const float* __restrict__ V,
    float* __restrict__ scorepart)   // [4][M_]
{
    __shared__ __align__(16) short lds[65536];   // A: [0,32768), B: [32768,65536) shorts

    const int tid = threadIdx.x;
    const int g = blockIdx.x;
    const int c = g & 7, q = g >> 3;            // XCD round-robin; 1024 % 8 == 0 -> bijective
    const int ntile = q & 3;                    // 4 ntiles walked consecutively per XCD
    const int mtile = (q >> 2) * 8 + c;
    const int row0 = mtile * 256, n0 = ntile * 256;
    const int bidx = row0 >> 12;                // 256-row tile never crosses batch (4096 % 256 == 0)

    const int lane = tid & 63;
    const int wv = tid >> 6;
    const int wm = wv >> 2, wn = wv & 3;        // 2M x 4N waves
    const int lm = lane & 15, quad = lane >> 4;

    // staging geometry: one GLLDS round = 512 thr x 16B = 64 rows x 128B
    const int srow = tid >> 3;                  // row within 64-row round
    const int lslot = (tid & 7) ^ (srow & 7);   // inverse swizzle on the GLOBAL source
    const short* aS = Abf + (size_t)(row0 + srow) * D_ + lslot * 8;
    const short* bS = W2T + (size_t)(n0  + srow) * D_ + lslot * 8;
    short* aD = lds + tid * 8;                  // linear LDS dest (wave-uniform base + lane*16)
    short* bD = lds + 32768 + tid * 8;

#define STG_A(kt, h, bf) do { \
    GLLDS(aS + (size_t)((h) * 128) * D_ + (kt) * 64,      aD + (bf) * 16384 + (h) * 8192); \
    GLLDS(aS + (size_t)((h) * 128 + 64) * D_ + (kt) * 64, aD + (bf) * 16384 + (h) * 8192 + 4096); \
} while (0)
#define STG_B(kt, h, bf) do { \
    GLLDS(bS + (size_t)((h) * 128) * D_ + (kt) * 64,      bD + (bf) * 16384 + (h) * 8192); \
    GLLDS(bS + (size_t)((h) * 128 + 64) * D_ + (kt) * 64, bD + (bf) * 16384 + (h) * 8192 + 4096); \
} while (0)
#define LDS_RD(off) (*(const short8*)(lds + (off)))
#define MFMA(a, b, c) __builtin_amdgcn_mfma_f32_16x16x32_bf16((a), (b), (c), 0, 0, 0)

    // swizzled read bases: phys_slot = (ks*4+quad) ^ (lm&7); ks=1 flips bit 32 (shorts)
    const int aB0 = (wm * 128 + lm) * 64 + (quad ^ (lm & 7)) * 8;
    const int aB1 = aB0 ^ 32;
    const int bB0 = 32768 + (wn * 64 + lm) * 64 + (quad ^ (lm & 7)) * 8;
    const int bB1 = bB0 ^ 32;

    float4v acc[8][4] = {};
    short8 Af[4][2], Bf[4][2];

    // ---- prologue: tile0 all 4 halves, then tile1 {B-lo, A-lo, B-hi} (3 halves = 6 loads in flight)
    STG_A(0, 0, 0); STG_A(0, 1, 0); STG_B(0, 0, 0); STG_B(0, 1, 0);
    STG_B(1, 0, 1); STG_A(1, 0, 1); STG_B(1, 1, 1);
    asm volatile("s_waitcnt vmcnt(6)" ::: "memory");
    __builtin_amdgcn_s_barrier();
    __builtin_amdgcn_sched_barrier(0);

    for (int t = 0; t < 16; ++t) {
        const int buf = t & 1;
        const int ab = buf * 16384;
        // ---------- phase 0: read A-lo frags + B-lo frags (12 ds_read), stage A-hi(t+1)
        #pragma unroll
        for (int mi = 0; mi < 4; ++mi) {
            Af[mi][0] = LDS_RD(ab + aB0 + mi * 1024);
            Af[mi][1] = LDS_RD(ab + aB1 + mi * 1024);
        }
        #pragma unroll
        for (int ni = 0; ni < 2; ++ni) {
            Bf[ni][0] = LDS_RD(ab + bB0 + ni * 1024);
            Bf[ni][1] = LDS_RD(ab + bB1 + ni * 1024);
        }
        if (t < 15) STG_A(t + 1, 1, (t + 1) & 1);
        __builtin_amdgcn_s_barrier();
        __builtin_amdgcn_s_setprio(1);
        #pragma unroll
        for (int mi = 0; mi < 4; ++mi)
            #pragma unroll
            for (int ni = 0; ni < 2; ++ni) {
                acc[mi][ni] = MFMA(Af[mi][0], Bf[ni][0], acc[mi][ni]);
                acc[mi][ni] = MFMA(Af[mi][1], Bf[ni][1], acc[mi][ni]);
            }
        __builtin_amdgcn_s_setprio(0);
        __builtin_amdgcn_s_barrier();
        // ---------- phase 1: read B-hi frags (4 ds_read); B fully consumed after this phase
        #pragma unroll
        for (int ni = 0; ni < 2; ++ni) {
            Bf[2 + ni][0] = LDS_RD(ab + bB0 + (2 + ni) * 1024);
            Bf[2 + ni][1] = LDS_RD(ab + bB1 + (2 + ni) * 1024);
        }
        __builtin_amdgcn_s_barrier();
        __builtin_amdgcn_s_setprio(1);
        #pragma unroll
        for (int mi = 0; mi < 4; ++mi)
            #pragma unroll
            for (int ni = 0; ni < 2; ++ni) {
                acc[mi][2 + ni] = MFMA(Af[mi][0], Bf[2 + ni][0], acc[mi][2 + ni]);
                acc[mi][2 + ni] = MFMA(Af[mi][1], Bf[2 + ni][1], acc[mi][2 + ni]);
            }
        __builtin_amdgcn_s_setprio(0);
        __builtin_amdgcn_s_barrier();
        // ---------- phase 2: read A-hi frags (8 ds_read; A consumed after), stage B-lo(t+2)
        #pragma unroll
        for (int mi = 0; mi < 4; ++mi) {
            Af[mi][0] = LDS_RD(ab + aB0 + 4096 + mi * 1024);
            Af[mi][1] = LDS_RD(ab + aB1 + 4096 + mi * 1024);
        }
        if (t < 14) STG_B(t + 2, 0, buf);
        __builtin_amdgcn_s_barrier();
        __builtin_amdgcn_s_setprio(1);
        #pragma unroll
        for (int mi = 0; mi < 4; ++mi)
            #pragma unroll
            for (int ni = 0; ni < 2; ++ni) {
                acc[4 + mi][ni] = MFMA(Af[mi][0], Bf[ni][0], acc[4 + mi][ni]);
                acc[4 + mi][ni] = MFMA(Af[mi][1], Bf[ni][1], acc[4 + mi][ni]);
            }
        __builtin_amdgcn_s_setprio(0);
        __builtin_amdgcn_s_barrier();
        // ---------- phase 3: no reads; stage A-lo(t+2)+B-hi(t+2); counted vmcnt at tile boundary
        if (t < 14) { STG_A(t + 2, 0, buf); STG_B(t + 2, 1, buf); }
        __builtin_amdgcn_s_barrier();
        __builtin_amdgcn_s_setprio(1);
        #pragma unroll
        for (int mi = 0; mi < 4; ++mi)
            #pragma unroll
            for (int ni = 0; ni < 2; ++ni) {
                acc[4 + mi][2 + ni] = MFMA(Af[mi][0], Bf[2 + ni][0], acc[4 + mi][2 + ni]);
                acc[4 + mi][2 + ni] = MFMA(Af[mi][1], Bf[2 + ni][1], acc[4 + mi][2 + ni]);
            }
        __builtin_amdgcn_s_setprio(0);
        if (t < 14)      { asm volatile("s_waitcnt vmcnt(6)" ::: "memory"); }
        else if (t == 14){ asm volatile("s_waitcnt vmcnt(0)" ::: "memory"); }
        __builtin_amdgcn_s_barrier();
        __builtin_amdgcn_sched_barrier(0);
    }

    // ---------- epilogue: score = sum_u tanh(acc + hb) * V over this block's 256 u's
    float* sbuf = (float*)lds;                  // [4][256] floats; LDS reads all drained
    float hbv[4], Vv[4];
    #pragma unroll
    for (int ni = 0; ni < 4; ++ni) {
        int U = n0 + wn * 64 + ni * 16 + lm;
        int o = bidx * U_ + U;
        hbv[ni] = hbp[o] + hbp[16384 + o] + hbp[32768 + o] + hbp[49152 + o];
        Vv[ni]  = V[U];
    }
    #pragma unroll
    for (int mi = 0; mi < 8; ++mi) {
        #pragma unroll
        for (int r = 0; r < 4; ++r) {
            float s = 0.f;
            #pragma unroll
            for (int ni = 0; ni < 4; ++ni)
                s += fast_tanh(acc[mi][ni][r] + hbv[ni]) * Vv[ni];
            #pragma unroll
            for (int off = 1; off < 16; off <<= 1)
                s += __shfl_xor(s, off, 64);
            if (lm == 0)
                sbuf[wn * 256 + wm * 128 + mi * 16 + quad * 4 + r] = s;
        }
    }
    __syncthreads();
    if (tid < 256)
        scorepart[(size_t)ntile * M_ + row0 + tid] =
            sbuf[tid] + sbuf[256 + tid] + sbuf[512 + tid] + sbuf[768 + tid];
}

// ---------------- kernel 3: fused softmax + context partials (verbatim round-3).
__global__ __launch_bounds__(256) void ctx_softmax(
        const float* __restrict__ scorepart,
        const float* __restrict__ bv,
        const short* __restrict__ encbf,
        float* __restrict__ out_attn,
        float* __restrict__ part)    // [512][1024] (in dead W2T region)
{
    __shared__ float sm[T_];          // 16 KB
    __shared__ float wsm[128];
    __shared__ float lacc[1024];
    __shared__ float red[8];
    const int x = blockIdx.x, tid = threadIdx.x;   // 0..255
    const int b = x & 15, tc = x >> 4;
    const int wvi = tid >> 6;
    const float bv0 = bv[0];
    float lmax = -1e30f;
    #pragma unroll
    for (int i = 0; i < 16; ++i) {
        int t = tid + i * 256;
        const float* sp = scorepart + (size_t)b * T_ + t;
        float s = bv0 + sp[0] + sp[M_] + sp[2 * (size_t)M_] + sp[3 * (size_t)M_];
        sm[t] = s;
        lmax = fmaxf(lmax, s);
    }
    #pragma unroll
    for (int off = 1; off < 64; off <<= 1) lmax = fmaxf(lmax, __shfl_xor(lmax, off, 64));
    if ((tid & 63) == 0) red[wvi] = lmax;
    __syncthreads();
    const float m = fmaxf(fmaxf(red[0], red[1]), fmaxf(red[2], red[3]));
    float lsum = 0.f;
    #pragma unroll
    for (int i = 0; i < 16; ++i) lsum += __expf(sm[tid + i * 256] - m);
    #pragma unroll
    for (int off = 1; off < 64; off <<= 1) lsum += __shfl_xor(lsum, off, 64);
    if ((tid & 63) == 0) red[4 + wvi] = lsum;
    __syncthreads();
    const float tot = (red[4] + red[5]) + (red[6] + red[7]);
    const float rinv = 1.f / tot;
    // own 128 rows: attn out + LDS weights
    if ((tid >> 7) == (tc & 1)) {
        int j = tid & 127;
        int t = tc * 128 + j;
        float w = __expf(sm[t] - m) * rinv;
        wsm[j] = w;
        out_attn[b * T_ + t] = w;
    }
    __syncthreads();
    // weighted sum over 128 rows, 2 rows/iter (parity split), 16B loads
    const int par = tid >> 7;
    const int d0 = (tid & 127) * 8;
    const short* e0 = encbf + (size_t)(b * T_ + tc * 128 + par) * D_ + d0;
    float4v a0 = {}, a1 = {};
    #pragma unroll 4
    for (int it = 0; it < 64; ++it) {
        short8 v = *(const short8*)(e0 + (size_t)it * 2 * D_);
        float w = wsm[it * 2 + par];
        a0[0] += w * bf2f(v[0]); a0[1] += w * bf2f(v[1]);
        a0[2] += w * bf2f(v[2]); a0[3] += w * bf2f(v[3]);
        a1[0] += w * bf2f(v[4]); a1[1] += w * bf2f(v[5]);
        a1[2] += w * bf2f(v[6]); a1[3] += w * bf2f(v[7]);
    }
    if (par) {
        *(float4v*)(lacc + (tid & 127) * 8)     = a0;
        *(float4v*)(lacc + (tid & 127) * 8 + 4) = a1;
    }
    __syncthreads();
    if (!par) {
        const float* l = lacc + tid * 8;
        a0[0] += l[0]; a0[1] += l[1]; a0[2] += l[2]; a0[3] += l[3];
        a1[0] += l[4]; a1[1] += l[5]; a1[2] += l[6]; a1[3] += l[7];
        float4v* pp = (float4v*)(part + (size_t)x * 1024 + tid * 8);
        pp[0] = a0; pp[1] = a1;
    }
}

// ---------------- kernel 4: reduce context partials (verbatim round-3)
__global__ void ctx_reduce_kernel(const float* __restrict__ part, float* __restrict__ ctx) {
    int gid = blockIdx.x * 256 + threadIdx.x;   // 0..16383
    int b = gid >> 10, d = gid & 1023;
    float s = 0.f;
    #pragma unroll
    for (int tc = 0; tc < 32; ++tc) s += part[(size_t)(tc * 16 + b) * 1024 + d];
    ctx[gid] = s;
}

extern "C" void kernel_launch(void* const* d_in, const int* in_sizes, int n_in,
                              void* d_out, int out_size, void* d_ws, size_t ws_size,
                              hipStream_t stream) {
    const float* h   = (const float*)d_in[0];
    const float* enc = (const float*)d_in[1];
    const float* W1  = (const float*)d_in[2];
    const float* b1  = (const float*)d_in[3];
    const float* W2  = (const float*)d_in[4];
    const float* b2  = (const float*)d_in[5];
    const float* V   = (const float*)d_in[6];
    const float* bv  = (const float*)d_in[7];
    float* out = (float*)d_out;                 // [0,16384) context, [16384,81920) attn
    float* ws  = (float*)d_ws;

    float* hbp       = ws;                      // 4*16384 floats (256 KB)
    float* scorepart = ws + 65536;              // [4][M_] floats (1 MB of 2 MB slot)
    short* W2T   = (short*)(ws + 65536 + 524288);          // 2 MB
    float* ctxpart   = (float*)W2T;             // ALIAS: W2T dead after gemm; scorepart stays live
    short* encbf = (short*)((char*)W2T + (size_t)U_ * D_ * 2);  // 128 MB

    prep_fused<<<16896, 256, 0, stream>>>(h, W1, b1, b2, W2, enc, hbp, W2T, encbf);
    gemm_score_8ph<<<1024, 512, 0, stream>>>(encbf, W2T, hbp, V, scorepart);
    ctx_softmax<<<512, 256, 0, stream>>>(scorepart, bv, encbf, out + 16384, ctxpart);
    ctx_reduce_kernel<<<64, 256, 0, stream>>>(ctxpart, out);
}

// Round 8
// 560.452 us; speedup vs baseline: 1.0400x; 1.0040x over previous
//
#include <hip/hip_runtime.h>
#include <hip/hip_bf16.h>
#include <math.h>

#define B_ 16
#define T_ 4096
#define D_ 1024
#define U_ 1024
#define M_ (B_*T_)   // 65536

typedef __attribute__((ext_vector_type(8))) short short8;
typedef __attribute__((ext_vector_type(4))) short short4v;
typedef __attribute__((ext_vector_type(4))) float float4v;

static __device__ __forceinline__ short f2bf(float f) {
    unsigned u = __builtin_bit_cast(unsigned, f);
    u += 0x7FFFu + ((u >> 16) & 1u);   // RNE
    return (short)(u >> 16);
}
static __device__ __forceinline__ float fast_tanh(float x) {
    float c = fminf(fmaxf(2.f * x, -30.f), 30.f);
    float t = __expf(c);
    return __fdividef(t - 1.f, t + 1.f);
}

#define GLLDS(GP, LP) __builtin_amdgcn_global_load_lds( \
    (const __attribute__((address_space(1))) void*)(GP), \
    (__attribute__((address_space(3))) void*)(LP), 16, 0, 0)

// ---------------- kernel 1 (prep): hb partials + W2 transpose/convert.
// enc conversion DELETED -- gemm converts f32->bf16 during A-staging; ctx reads f32.
__global__ void prep_fused(const float* __restrict__ h, const float* __restrict__ W1,
                           const float* __restrict__ b1, const float* __restrict__ b2,
                           const float* __restrict__ W2,
                           float* __restrict__ hbp, short* __restrict__ W2T) {
    int bx = blockIdx.x;
    if (bx < 256) {
        // ---- hb partials, K split 4 ways
        int kc = bx >> 6;
        int gid = (bx & 63) * 256 + threadIdx.x;
        int b = gid >> 10, u = gid & 1023;
        const float* hr = h + b * D_ + kc * 256;
        const float* w = W1 + (size_t)(kc * 256) * U_ + u;
        float s0 = 0.f, s1 = 0.f, s2 = 0.f, s3 = 0.f;
        for (int k = 0; k < 256; k += 4) {
            s0 += hr[k+0] * w[(size_t)(k+0) * U_];
            s1 += hr[k+1] * w[(size_t)(k+1) * U_];
            s2 += hr[k+2] * w[(size_t)(k+2) * U_];
            s3 += hr[k+3] * w[(size_t)(k+3) * U_];
        }
        float s = ((s0 + s1) + (s2 + s3));
        if (kc == 0) s += b1[u] + b2[u];
        hbp[kc * 16384 + gid] = s;
    } else {
        // ---- convert_w2t (transpose to [U][D])
        __shared__ short t[64][65];
        int x = bx - 256;
        int k0 = (x >> 4) * 64, u0 = (x & 15) * 64;
        int tx = threadIdx.x & 63, ty = threadIdx.x >> 6;
        #pragma unroll
        for (int r = 0; r < 16; ++r) {
            int kk = ty * 16 + r;
            t[kk][tx] = f2bf(W2[(size_t)(k0 + kk) * U_ + u0 + tx]);
        }
        __syncthreads();
        #pragma unroll
        for (int r = 0; r < 16; ++r) {
            int uu = ty * 16 + r;
            W2T[(size_t)(u0 + uu) * D_ + k0 + tx] = t[tx][uu];
        }
    }
}

// ---------------- kernel 2: 256x256-tile 8-phase bf16 GEMM + tanh*V epilogue.
// A-operand now read as f32 from enc and converted in-register during staging
// (reg-stage: global f32 loads -> f2bf -> ds_write_b128), producing the byte-identical
// LDS image the GLLDS path produced. B stays on GLLDS. Phases/barriers/MFMA untouched.
// Hand vmcnt removed: compiler waits before each cvt-use drain the correct prefix
// (A-hi loads at ph0(t) are younger than B(t+1) GLLDS from t-1, so the ph3 write-wait
// transitively guarantees B(t+1) arrived). Added lgkmcnt(0) before tile-end barrier
// so ds_writes are visible across waves.
__global__ __launch_bounds__(512, 2) void gemm_score_8ph(
    const float* __restrict__ encf,  // enc f32 [M_, D_]
    const short* __restrict__ W2T,   // bf16 [U_, D_]
    const float* __restrict__ hbp,   // [4][B_, U_]
    const float* __restrict__ V,
    float* __restrict__ scorepart)   // [4][M_]
{
    __shared__ __align__(16) short lds[65536];   // A: [0,32768), B: [32768,65536) shorts

    const int tid = threadIdx.x;
    const int g = blockIdx.x;
    const int c = g & 7, q = g >> 3;            // XCD round-robin; 1024 % 8 == 0 -> bijective
    const int ntile = q & 3;
    const int mtile = (q >> 2) * 8 + c;
    const int row0 = mtile * 256, n0 = ntile * 256;
    const int bidx = row0 >> 12;

    const int lane = tid & 63;
    const int wv = tid >> 6;
    const int wm = wv >> 2, wn = wv & 3;        // 2M x 4N waves
    const int lm = lane & 15, quad = lane >> 4;

    // staging geometry: one round = 512 thr x 8 elems = 64 rows x 128B(bf16)
    const int srow = tid >> 3;
    const int lslot = (tid & 7) ^ (srow & 7);   // inverse swizzle on the GLOBAL source
    const float* Aenc = encf + (size_t)(row0 + srow) * D_ + lslot * 8;   // f32 source
    const short* bS = W2T + (size_t)(n0 + srow) * D_ + lslot * 8;
    short* bD = lds + 32768 + tid * 8;

#define STG_B(kt, h, bf) do { \
    GLLDS(bS + (size_t)((h) * 128) * D_ + (kt) * 64,      bD + (bf) * 16384 + (h) * 8192); \
    GLLDS(bS + (size_t)((h) * 128 + 64) * D_ + (kt) * 64, bD + (bf) * 16384 + (h) * 8192 + 4096); \
} while (0)
// issue 4 float4 loads for A half-tile hh of K-tile kt into reg set R (R##0..R##3)
#define LDA_ISSUE(R, kt, hh) do { \
    const float* _p0 = Aenc + (size_t)((hh) * 128) * D_ + (kt) * 64; \
    const float* _p1 = _p0 + (size_t)64 * D_; \
    R##0 = *(const float4v*)_p0; \
    R##1 = *(const float4v*)(_p0 + 4); \
    R##2 = *(const float4v*)_p1; \
    R##3 = *(const float4v*)(_p1 + 4); \
} while (0)
// convert reg set R to bf16 and write the same LDS slots GLLDS used
#define LDA_WRITE(R, hh, bfi) do { \
    short8 _w0, _w1; \
    _w0[0]=f2bf(R##0[0]); _w0[1]=f2bf(R##0[1]); _w0[2]=f2bf(R##0[2]); _w0[3]=f2bf(R##0[3]); \
    _w0[4]=f2bf(R##1[0]); _w0[5]=f2bf(R##1[1]); _w0[6]=f2bf(R##1[2]); _w0[7]=f2bf(R##1[3]); \
    _w1[0]=f2bf(R##2[0]); _w1[1]=f2bf(R##2[1]); _w1[2]=f2bf(R##2[2]); _w1[3]=f2bf(R##2[3]); \
    _w1[4]=f2bf(R##3[0]); _w1[5]=f2bf(R##3[1]); _w1[6]=f2bf(R##3[2]); _w1[7]=f2bf(R##3[3]); \
    *(short8*)(lds + (bfi) * 16384 + (hh) * 8192 + tid * 8) = _w0; \
    *(short8*)(lds + (bfi) * 16384 + (hh) * 8192 + 4096 + tid * 8) = _w1; \
} while (0)
#define LDS_RD(off) (*(const short8*)(lds + (off)))
#define MFMA(a, b, c) __builtin_amdgcn_mfma_f32_16x16x32_bf16((a), (b), (c), 0, 0, 0)

    // swizzled read bases
    const int aB0 = (wm * 128 + lm) * 64 + (quad ^ (lm & 7)) * 8;
    const int aB1 = aB0 ^ 32;
    const int bB0 = 32768 + (wn * 64 + lm) * 64 + (quad ^ (lm & 7)) * 8;
    const int bB1 = bB0 ^ 32;

    float4v acc[8][4] = {};
    short8 Af[4][2], Bf[4][2];
    float4v rLO0, rLO1, rLO2, rLO3;   // A-lo staging regs
    float4v rHI0, rHI1, rHI2, rHI3;   // A-hi staging regs

    // ---- prologue. Issue order matters: B(0) first (oldest), so the compiler's wait
    // before the A(0) cvt-use transitively drains B(0) before the first barrier.
    STG_B(0, 0, 0); STG_B(0, 1, 0);
    LDA_ISSUE(rLO, 0, 0); LDA_ISSUE(rHI, 0, 1);
    STG_B(1, 0, 1); STG_B(1, 1, 1);
    LDA_WRITE(rLO, 0, 0);             // waits rLO loads -> drains B(0) too
    LDA_WRITE(rHI, 1, 0);
    LDA_ISSUE(rLO, 1, 0);             // A-lo(1)
    asm volatile("s_waitcnt lgkmcnt(0)" ::: "memory");
    __builtin_amdgcn_s_barrier();
    __builtin_amdgcn_sched_barrier(0);

    for (int t = 0; t < 16; ++t) {
        const int buf = t & 1;
        const int ab = buf * 16384;
        // ---------- phase 0: read A-lo + B-lo frags (12 ds_read), issue A-hi(t+1) loads
        #pragma unroll
        for (int mi = 0; mi < 4; ++mi) {
            Af[mi][0] = LDS_RD(ab + aB0 + mi * 1024);
            Af[mi][1] = LDS_RD(ab + aB1 + mi * 1024);
        }
        #pragma unroll
        for (int ni = 0; ni < 2; ++ni) {
            Bf[ni][0] = LDS_RD(ab + bB0 + ni * 1024);
            Bf[ni][1] = LDS_RD(ab + bB1 + ni * 1024);
        }
        if (t < 15) LDA_ISSUE(rHI, t + 1, 1);
        __builtin_amdgcn_s_barrier();
        __builtin_amdgcn_s_setprio(1);
        #pragma unroll
        for (int mi = 0; mi < 4; ++mi)
            #pragma unroll
            for (int ni = 0; ni < 2; ++ni) {
                acc[mi][ni] = MFMA(Af[mi][0], Bf[ni][0], acc[mi][ni]);
                acc[mi][ni] = MFMA(Af[mi][1], Bf[ni][1], acc[mi][ni]);
            }
        __builtin_amdgcn_s_setprio(0);
        __builtin_amdgcn_s_barrier();
        // ---------- phase 1: read B-hi frags (4 ds_read)
        #pragma unroll
        for (int ni = 0; ni < 2; ++ni) {
            Bf[2 + ni][0] = LDS_RD(ab + bB0 + (2 + ni) * 1024);
            Bf[2 + ni][1] = LDS_RD(ab + bB1 + (2 + ni) * 1024);
        }
        __builtin_amdgcn_s_barrier();
        __builtin_amdgcn_s_setprio(1);
        #pragma unroll
        for (int mi = 0; mi < 4; ++mi)
            #pragma unroll
            for (int ni = 0; ni < 2; ++ni) {
                acc[mi][2 + ni] = MFMA(Af[mi][0], Bf[2 + ni][0], acc[mi][2 + ni]);
                acc[mi][2 + ni] = MFMA(Af[mi][1], Bf[2 + ni][1], acc[mi][2 + ni]);
            }
        __builtin_amdgcn_s_setprio(0);
        __builtin_amdgcn_s_barrier();
        // ---------- phase 2: read A-hi frags (8 ds_read), stage B-lo(t+2)
        #pragma unroll
        for (int mi = 0; mi < 4; ++mi) {
            Af[mi][0] = LDS_RD(ab + aB0 + 4096 + mi * 1024);
            Af[mi][1] = LDS_RD(ab + aB1 + 4096 + mi * 1024);
        }
        if (t < 14) STG_B(t + 2, 0, buf);
        __builtin_amdgcn_s_barrier();
        __builtin_amdgcn_s_setprio(1);
        #pragma unroll
        for (int mi = 0; mi < 4; ++mi)
            #pragma unroll
            for (int ni = 0; ni < 2; ++ni) {
                acc[4 + mi][ni] = MFMA(Af[mi][0], Bf[ni][0], acc[4 + mi][ni]);
                acc[4 + mi][ni] = MFMA(Af[mi][1], Bf[ni][1], acc[4 + mi][ni]);
            }
        __builtin_amdgcn_s_setprio(0);
        __builtin_amdgcn_s_barrier();
        // ---------- phase 3 (no ds_reads): write A-lo(t+1), issue A-lo(t+2)+B-hi(t+2),
        //            write A-hi(t+1). Writes target buf^1 (not read during t).
        if (t < 15) LDA_WRITE(rLO, 0, (t + 1) & 1);
        if (t < 14) { LDA_ISSUE(rLO, t + 2, 0); STG_B(t + 2, 1, buf); }
        if (t < 15) LDA_WRITE(rHI, 1, (t + 1) & 1);
        __builtin_amdgcn_s_barrier();
        __builtin_amdgcn_s_setprio(1);
        #pragma unroll
        for (int mi = 0; mi < 4; ++mi)
            #pragma unroll
            for (int ni = 0; ni < 2; ++ni) {
                acc[4 + mi][2 + ni] = MFMA(Af[mi][0], Bf[2 + ni][0], acc[4 + mi][2 + ni]);
                acc[4 + mi][2 + ni] = MFMA(Af[mi][1], Bf[2 + ni][1], acc[4 + mi][2 + ni]);
            }
        __builtin_amdgcn_s_setprio(0);
        asm volatile("s_waitcnt lgkmcnt(0)" ::: "memory");   // ds_writes visible block-wide
        __builtin_amdgcn_s_barrier();
        __builtin_amdgcn_sched_barrier(0);
    }

    // ---------- epilogue: score = sum_u tanh(acc + hb) * V over this block's 256 u's
    float* sbuf = (float*)lds;
    float hbv[4], Vv[4];
    #pragma unroll
    for (int ni = 0; ni < 4; ++ni) {
        int U = n0 + wn * 64 + ni * 16 + lm;
        int o = bidx * U_ + U;
        hbv[ni] = hbp[o] + hbp[16384 + o] + hbp[32768 + o] + hbp[49152 + o];
        Vv[ni]  = V[U];
    }
    #pragma unroll
    for (int mi = 0; mi < 8; ++mi) {
        #pragma unroll
        for (int r = 0; r < 4; ++r) {
            float s = 0.f;
            #pragma unroll
            for (int ni = 0; ni < 4; ++ni)
                s += fast_tanh(acc[mi][ni][r] + hbv[ni]) * Vv[ni];
            #pragma unroll
            for (int off = 1; off < 16; off <<= 1)
                s += __shfl_xor(s, off, 64);
            if (lm == 0)
                sbuf[wn * 256 + wm * 128 + mi * 16 + quad * 4 + r] = s;
        }
    }
    __syncthreads();
    if (tid < 256)
        scorepart[(size_t)ntile * M_ + row0 + tid] =
            sbuf[tid] + sbuf[256 + tid] + sbuf[512 + tid] + sbuf[768 + tid];
}

// ---------------- kernel 3: fused softmax + context partials; enc read as f32.
__global__ __launch_bounds__(256) void ctx_softmax(
        const float* __restrict__ scorepart,
        const float* __restrict__ bv,
        const float* __restrict__ enc,
        float* __restrict__ out_attn,
        float* __restrict__ part)    // [512][1024] (in dead W2T region)
{
    __shared__ float sm[T_];          // 16 KB
    __shared__ float wsm[128];
    __shared__ float lacc[1024];
    __shared__ float red[8];
    const int x = blockIdx.x, tid = threadIdx.x;   // 0..255
    const int b = x & 15, tc = x >> 4;
    const int wvi = tid >> 6;
    const float bv0 = bv[0];
    float lmax = -1e30f;
    #pragma unroll
    for (int i = 0; i < 16; ++i) {
        int t = tid + i * 256;
        const float* sp = scorepart + (size_t)b * T_ + t;
        float s = bv0 + sp[0] + sp[M_] + sp[2 * (size_t)M_] + sp[3 * (size_t)M_];
        sm[t] = s;
        lmax = fmaxf(lmax, s);
    }
    #pragma unroll
    for (int off = 1; off < 64; off <<= 1) lmax = fmaxf(lmax, __shfl_xor(lmax, off, 64));
    if ((tid & 63) == 0) red[wvi] = lmax;
    __syncthreads();
    const float m = fmaxf(fmaxf(red[0], red[1]), fmaxf(red[2], red[3]));
    float lsum = 0.f;
    #pragma unroll
    for (int i = 0; i < 16; ++i) lsum += __expf(sm[tid + i * 256] - m);
    #pragma unroll
    for (int off = 1; off < 64; off <<= 1) lsum += __shfl_xor(lsum, off, 64);
    if ((tid & 63) == 0) red[4 + wvi] = lsum;
    __syncthreads();
    const float tot = (red[4] + red[5]) + (red[6] + red[7]);
    const float rinv = 1.f / tot;
    // own 128 rows: attn out + LDS weights
    if ((tid >> 7) == (tc & 1)) {
        int j = tid & 127;
        int t = tc * 128 + j;
        float w = __expf(sm[t] - m) * rinv;
        wsm[j] = w;
        out_attn[b * T_ + t] = w;
    }
    __syncthreads();
    // weighted sum over 128 rows, 2 rows/iter (parity split), 32B f32 loads
    const int par = tid >> 7;
    const int d0 = (tid & 127) * 8;
    const float* e0 = enc + (size_t)(b * T_ + tc * 128 + par) * D_ + d0;
    float4v a0 = {}, a1 = {};
    #pragma unroll 4
    for (int it = 0; it < 64; ++it) {
        float4v v0 = *(const float4v*)(e0 + (size_t)it * 2 * D_);
        float4v v1 = *(const float4v*)(e0 + (size_t)it * 2 * D_ + 4);
        float w = wsm[it * 2 + par];
        a0[0] += w * v0[0]; a0[1] += w * v0[1];
        a0[2] += w * v0[2]; a0[3] += w * v0[3];
        a1[0] += w * v1[0]; a1[1] += w * v1[1];
        a1[2] += w * v1[2]; a1[3] += w * v1[3];
    }
    if (par) {
        *(float4v*)(lacc + (tid & 127) * 8)     = a0;
        *(float4v*)(lacc + (tid & 127) * 8 + 4) = a1;
    }
    __syncthreads();
    if (!par) {
        const float* l = lacc + tid * 8;
        a0[0] += l[0]; a0[1] += l[1]; a0[2] += l[2]; a0[3] += l[3];
        a1[0] += l[4]; a1[1] += l[5]; a1[2] += l[6]; a1[3] += l[7];
        float4v* pp = (float4v*)(part + (size_t)x * 1024 + tid * 8);
        pp[0] = a0; pp[1] = a1;
    }
}

// ---------------- kernel 4: reduce context partials (verbatim)
__global__ void ctx_reduce_kernel(const float* __restrict__ part, float* __restrict__ ctx) {
    int gid = blockIdx.x * 256 + threadIdx.x;   // 0..16383
    int b = gid >> 10, d = gid & 1023;
    float s = 0.f;
    #pragma unroll
    for (int tc = 0; tc < 32; ++tc) s += part[(size_t)(tc * 16 + b) * 1024 + d];
    ctx[gid] = s;
}

extern "C" void kernel_launch(void* const* d_in, const int* in_sizes, int n_in,
                              void* d_out, int out_size, void* d_ws, size_t ws_size,
                              hipStream_t stream) {
    const float* h   = (const float*)d_in[0];
    const float* enc = (const float*)d_in[1];
    const float* W1  = (const float*)d_in[2];
    const float* b1  = (const float*)d_in[3];
    const float* W2  = (const float*)d_in[4];
    const float* b2  = (const float*)d_in[5];
    const float* V   = (const float*)d_in[6];
    const float* bv  = (const float*)d_in[7];
    float* out = (float*)d_out;                 // [0,16384) context, [16384,81920) attn
    float* ws  = (float*)d_ws;

    float* hbp       = ws;                      // 4*16384 floats (256 KB)
    float* scorepart = ws + 65536;              // [4][M_] floats (1 MB of 2 MB slot)
    short* W2T   = (short*)(ws + 65536 + 524288);          // 2 MB
    float* ctxpart   = (float*)W2T;             // ALIAS: W2T dead after gemm; scorepart stays live

    prep_fused<<<512, 256, 0, stream>>>(h, W1, b1, b2, W2, hbp, W2T);
    gemm_score_8ph<<<1024, 512, 0, stream>>>(enc, W2T, hbp, V, scorepart);
    ctx_softmax<<<512, 256, 0, stream>>>(scorepart, bv, enc, out + 16384, ctxpart);
    ctx_reduce_kernel<<<64, 256, 0, stream>>>(ctxpart, out);
}